// Round 1
// 455.775 us; speedup vs baseline: 1.0084x; 1.0084x over previous
//
#include <hip/hip_runtime.h>
#include <hip/hip_bf16.h>
#include <cstdint>
#include <cstddef>

#define B_ 2
#define S_ 2048
#define D_ 2048
#define H_ 16
#define DK_ 128
#define M_ (B_*S_)   // 4096

typedef __attribute__((ext_vector_type(8))) __bf16 bf16x8;
typedef __attribute__((ext_vector_type(4))) float f32x4;
typedef __attribute__((ext_vector_type(16))) float f32x16;

__device__ __forceinline__ unsigned short f2bf(float f) {
  union { float f; unsigned int u; } v; v.f = f;
  unsigned int r = (v.u + 0x7fffu + ((v.u >> 16) & 1u)) >> 16;
  return (unsigned short)r;
}
__device__ __forceinline__ float bf2f(unsigned short b) {
  union { unsigned int u; float f; } v; v.u = ((unsigned int)b) << 16;
  return v.f;
}

// async global->LDS, 16B per lane; LDS dest is wave-uniform base + lane*16
__device__ __forceinline__ void gld16(const void* g, void* l) {
  __builtin_amdgcn_global_load_lds(
      (const __attribute__((address_space(1))) unsigned int*)g,
      (__attribute__((address_space(3))) unsigned int*)l, 16, 0, 0);
}

// ---------------- fp32 -> bf16 ----------------
__global__ void cvt_bf16(const float* __restrict__ src, unsigned short* __restrict__ dst, int n) {
  int i = (blockIdx.x * blockDim.x + threadIdx.x) * 4;
  if (i + 3 < n) {
    float4 v = *(const float4*)(src + i);
    dst[i+0] = f2bf(v.x); dst[i+1] = f2bf(v.y);
    dst[i+2] = f2bf(v.z); dst[i+3] = f2bf(v.w);
  }
}

// ---------------- 256x256 8-phase GEMM: C(MxN) = A(MxK) * Bt(NxK)^T ----------------
// 512 threads = 8 waves (2M x 4N), BK=64 as two K-halves of 32, 2 LDS bufs (128 KiB).
// Per phase: ds_read subtile || stage 1 half-tile (2x global_load_lds) -> barrier ->
// lgkmcnt(0) -> setprio(1) + 16 MFMA -> barrier. Counted vmcnt(4) once per K-tile
// (never 0 in steady state). LDS swizzle: 16B chunk qk ^= (row>>1)&3; realized by
// pre-swizzled GLOBAL source (gld_lds dest is linear). Requires K%128==0, M%256==0, N%256==0.
template<int WRITE_BF16>
__global__ __launch_bounds__(512, 2) void gemm8p(const unsigned short* __restrict__ A,
                                                 const unsigned short* __restrict__ W0,
                                                 const unsigned short* __restrict__ W1,
                                                 const unsigned short* __restrict__ W2,
                                                 void* __restrict__ C0, void* __restrict__ C1,
                                                 void* __restrict__ C2,
                                                 int M, int N, int K) {
  __shared__ unsigned short sA[2][2][256 * 32];   // [buf][khalf][256 rows x 32 k] 16KB each
  __shared__ unsigned short sB[2][2][256 * 32];
  const int z = blockIdx.z;
  const unsigned short* Bt = (z == 0) ? W0 : (z == 1) ? W1 : W2;
  void* Cout = (z == 0) ? C0 : (z == 1) ? C1 : C2;

  const int tid  = threadIdx.x;
  const int lane = tid & 63;
  const int wid  = tid >> 6;
  const int wm = wid >> 2, wn = wid & 3;           // wave tile: rows wm*128, cols wn*64
  const int l16 = lane & 15, quad = lane >> 4;
  const int col16 = quad ^ ((lane >> 1) & 3);      // swizzled 16B chunk for frag reads
  const int qk_log = (lane & 3) ^ ((lane >> 3) & 3); // inverse swizzle for staging source
  const int srow = lane >> 2;                      // staging row within 16-row group
  const int bm = blockIdx.y * 256, bn = blockIdx.x * 256;
  const int NT = K >> 6;                           // K-tiles of 64

  f32x4 acc[8][4];
  #pragma unroll
  for (int i = 0; i < 8; ++i)
    #pragma unroll
    for (int j = 0; j < 4; ++j)
      acc[i][j] = (f32x4){0.f, 0.f, 0.f, 0.f};

  // stage one K-half (256 rows x 32 k = 16KB): 2 wave-issues of 1KB per wave.
  // LDS linear; global source pre-swizzled so read-side chunk XOR sees correct data.
  auto stage = [&](const unsigned short* __restrict__ g, int rowbase,
                   unsigned short* l, int t, int kh) {
    const unsigned short* src = g + (size_t)rowbase * K + t * 64 + kh * 32 + qk_log * 8;
    #pragma unroll
    for (int p = 0; p < 2; ++p) {
      const int i = wid * 2 + p;                   // issue 0..15, 16 rows each
      gld16(src + (size_t)(i * 16 + srow) * K, l + i * 512);
    }
  };

  // prologue: tile0 fully, tile1 kh0; wait tile0 (leave 4 loads in flight)
  stage(A,  bm, &sA[0][0][0], 0, 0);
  stage(Bt, bn, &sB[0][0][0], 0, 0);
  stage(A,  bm, &sA[0][1][0], 0, 1);
  stage(Bt, bn, &sB[0][1][0], 0, 1);
  stage(A,  bm, &sA[1][0][0], 1, 0);
  stage(Bt, bn, &sB[1][0][0], 1, 0);
  asm volatile("s_waitcnt vmcnt(4)" ::: "memory");
  __builtin_amdgcn_s_barrier();

  for (int t = 0; t < NT; ++t) {
    const int buf = t & 1;
    bf16x8 bfrag[4];                               // B frags persist across mh phases
    #pragma unroll
    for (int ph = 0; ph < 4; ++ph) {
      const int ks = ph >> 1;                      // K-half consumed this phase
      const int mh = ph & 1;                       // wave-tile M-half this phase
      // ds_read register subtile (4 or 8 x ds_read_b128)
      bf16x8 afrag[4];
      const unsigned short* aP = &sA[buf][ks][0] +
          (size_t)((wm * 128 + mh * 64 + l16) * 4 + col16) * 8;
      #pragma unroll
      for (int mf = 0; mf < 4; ++mf)
        afrag[mf] = *(const bf16x8*)(aP + mf * 512);
      if (mh == 0) {
        const unsigned short* bP = &sB[buf][ks][0] +
            (size_t)((wn * 64 + l16) * 4 + col16) * 8;
        #pragma unroll
        for (int nf = 0; nf < 4; ++nf)
          bfrag[nf] = *(const bf16x8*)(bP + nf * 512);
      }
      // stage: slot went dead >=1 barrier ago (kh0 dies after ph1, kh1 after ph3)
      if (ph == 0)      { if (t + 1 < NT) stage(A,  bm, &sA[buf ^ 1][1][0], t + 1, 1); }
      else if (ph == 1) { if (t + 1 < NT) stage(Bt, bn, &sB[buf ^ 1][1][0], t + 1, 1); }
      else if (ph == 2) { if (t + 2 < NT) stage(A,  bm, &sA[buf][0][0],     t + 2, 0); }
      else              { if (t + 2 < NT) stage(Bt, bn, &sB[buf][0][0],     t + 2, 0); }

      __builtin_amdgcn_s_barrier();
      asm volatile("s_waitcnt lgkmcnt(0)" ::: "memory");
      __builtin_amdgcn_s_setprio(1);
      #pragma unroll
      for (int nf = 0; nf < 4; ++nf)
        #pragma unroll
        for (int mf = 0; mf < 4; ++mf)
          acc[mh * 4 + mf][nf] = __builtin_amdgcn_mfma_f32_16x16x32_bf16(
              afrag[mf], bfrag[nf], acc[mh * 4 + mf][nf], 0, 0, 0);
      __builtin_amdgcn_s_setprio(0);
      if (ph == 3) {  // once per K-tile: counted wait; tile t+1 fully landed after this
        if (t + 2 < NT) asm volatile("s_waitcnt vmcnt(4)" ::: "memory");
        else            asm volatile("s_waitcnt vmcnt(0)" ::: "memory");
      }
      __builtin_amdgcn_s_barrier();
    }
  }

  #pragma unroll
  for (int mf = 0; mf < 8; ++mf) {
    const int row = bm + wm * 128 + mf * 16 + quad * 4;
    #pragma unroll
    for (int nf = 0; nf < 4; ++nf) {
      const int col = bn + wn * 64 + nf * 16 + l16;
      #pragma unroll
      for (int r = 0; r < 4; ++r) {
        if (WRITE_BF16)
          ((unsigned short*)Cout)[(size_t)(row + r) * N + col] = f2bf(acc[mf][nf][r]);
        else
          ((float*)Cout)[(size_t)(row + r) * N + col] = acc[mf][nf][r];
      }
    }
  }
}

// ---------------- RoPE (in-place on bf16 Q and K) ----------------
__global__ void rope_kernel(unsigned short* __restrict__ Q, unsigned short* __restrict__ K,
                            const int* __restrict__ pos) {
  int idx = blockIdx.x * blockDim.x + threadIdx.x;
  int i = idx & 63;
  int h = (idx >> 6) & (H_ - 1);
  int s = (idx >> 10) & (S_ - 1);
  int b = idx >> 21;
  float p = (float)pos[s];
  float inv = expf(-(float)i * (9.210340371976184f / 64.0f));
  float ang = p * inv;
  float sn, cs;
  sincosf(ang, &sn, &cs);
  size_t base = (((size_t)b * S_ + s) * D_) + (size_t)h * DK_ + 2 * i;
  float x1 = bf2f(Q[base]), x2 = bf2f(Q[base + 1]);
  Q[base]     = f2bf(x1 * cs - x2 * sn);
  Q[base + 1] = f2bf(x1 * sn + x2 * cs);
  x1 = bf2f(K[base]); x2 = bf2f(K[base + 1]);
  K[base]     = f2bf(x1 * cs - x2 * sn);
  K[base + 1] = f2bf(x1 * sn + x2 * cs);
}

// ---------------- V transpose: per b, VT[col][m] = V[m][col] ----------------
__global__ __launch_bounds__(256) void transpose_bf16(const unsigned short* __restrict__ src,
                                                      unsigned short* __restrict__ dst) {
  __shared__ unsigned short sT[64 * 64];
  const int b = blockIdx.y;
  const int tx = blockIdx.x & 31, ty = blockIdx.x >> 5;
  const size_t base = (size_t)b * 2048 * 2048;
  const int m0 = ty * 64, c0 = tx * 64;
  const int tid = threadIdx.x;
  #pragma unroll
  for (int c = 0; c < 2; ++c) {
    int idx = tid + c * 256;
    int row = idx >> 3;               // 0..63 (m)
    int chk = idx & 7;                // col chunk
    uint4 v = *(const uint4*)(src + base + (size_t)(m0 + row) * 2048 + c0 + chk * 8);
    *(uint4*)(sT + row * 64 + ((chk ^ (row & 7)) * 8)) = v;
  }
  __syncthreads();
  #pragma unroll
  for (int c = 0; c < 2; ++c) {
    int idx = tid + c * 256;
    int orow = idx >> 3;              // output row = col index
    int ocol = (idx & 7) * 8;         // output col = m index
    unsigned short tmp[8];
    #pragma unroll
    for (int j = 0; j < 8; ++j) {
      int lr = ocol + j;              // logical row (m)
      int lc = orow;                  // logical col
      tmp[j] = sT[lr * 64 + (((lc >> 3) ^ (lr & 7)) * 8) + (lc & 7)];
    }
    *(uint4*)(dst + base + (size_t)(c0 + orow) * 2048 + m0 + ocol) = *(const uint4*)tmp;
  }
}

// ---------------- Flash attention (causal), 32x32 MFMA, pipelined staging ----------------
__global__ __launch_bounds__(256, 2) void flash_attn(const unsigned short* __restrict__ Q,
                                                     const unsigned short* __restrict__ K,
                                                     const unsigned short* __restrict__ VT,
                                                     unsigned short* __restrict__ O) {
  __shared__ unsigned short sK[2][64 * 128];   // [buf][key][feat-chunk swz] 16KB each
  __shared__ unsigned short sVT[2][128 * 64];  // [buf][feat][key-chunk swz] 16KB each
  __shared__ unsigned short sP[4][32 * 64];    // per-wave 32x64 P, swz, 4KB each

  const int tid = threadIdx.x, lane = tid & 63, wid = tid >> 6;
  const int half = lane >> 5, l32 = lane & 31;
  const int qi = 15 - (blockIdx.x & 15);       // 16 q-blocks of 128 rows; heavy first
  const int bh = blockIdx.x >> 4;
  const int h = bh & (H_ - 1), b = bh >> 4;
  const int qw = qi * 128 + wid * 32;          // this wave's first Q row
  const size_t qkbase = ((size_t)b * S_) * D_ + (size_t)h * DK_;
  const unsigned short* Qg = Q + qkbase;
  const unsigned short* Kg = K + qkbase;
  const unsigned short* VTg = VT + (size_t)bh * DK_ * S_;   // [dk][s]
  unsigned short* Og = O + qkbase;
  unsigned short* sPw = sP[wid];

  const int kKeySub = lane >> 4;               // K: 4 key rows per issue
  const int kPhys   = lane & 15;               // 16 chunks per 256B K row
  const int vFeatSub = lane >> 3;              // VT: 8 feat rows per issue
  const int vPhys    = lane & 7;               // 8 chunks per 128B VT row

  bf16x8 qf[8];
  #pragma unroll
  for (int ks = 0; ks < 8; ++ks)
    qf[ks] = *(const bf16x8*)(Qg + (size_t)(qw + l32) * D_ + ks * 16 + half * 8);

  union { unsigned short u[8]; bf16x8 v; } onesu;
  #pragma unroll
  for (int j = 0; j < 8; ++j) onesu.u[j] = 0x3F80;  // bf16 1.0
  const bf16x8 ones = onesu.v;

  f32x16 Oacc[4];
  #pragma unroll
  for (int ft = 0; ft < 4; ++ft)
    #pragma unroll
    for (int r = 0; r < 16; ++r) Oacc[ft][r] = 0.f;
  f32x16 l_acc;
  #pragma unroll
  for (int r = 0; r < 16; ++r) l_acc[r] = 0.f;
  const float scale = 0.08838834764831845f;    // 1/sqrt(128)

  const int nkb = 2 * (qi + 1);

  auto stage = [&](int kb) {
    const int k0 = kb * 64;
    unsigned short* bK = sK[kb & 1];
    unsigned short* bV = sVT[kb & 1];
    #pragma unroll
    for (int p = 0; p < 4; ++p) {
      int issue = wid * 4 + p;                 // 0..15
      int key = issue * 4 + kKeySub;
      int logiK = (kPhys & 8) | ((kPhys ^ key) & 7);
      gld16(Kg + (size_t)(k0 + key) * D_ + logiK * 8, bK + issue * 512);
      int feat = issue * 8 + vFeatSub;
      int logiV = vPhys ^ (feat & 7);
      gld16(VTg + (size_t)feat * S_ + k0 + logiV * 8, bV + issue * 512);
    }
  };

  stage(0);

  for (int kb = 0; kb < nkb; ++kb) {
    __syncthreads();   // drains vmcnt: buf[kb&1] ready; prior reads of other buf done
    if (kb + 1 < nkb) stage(kb + 1);

    const int k0 = kb * 64;
    if (k0 > qw + 31) continue;                // fully-masked for this wave (uniform)

    const unsigned short* bK = sK[kb & 1];
    const unsigned short* bV = sVT[kb & 1];

    f32x16 sc[2];
    #pragma unroll
    for (int t = 0; t < 2; ++t)
      #pragma unroll
      for (int r = 0; r < 16; ++r) sc[t][r] = 0.f;
    #pragma unroll
    for (int ks = 0; ks < 8; ++ks) {
      const int logi = ks * 2 + half;
      #pragma unroll
      for (int t = 0; t < 2; ++t) {
        const int key = t * 32 + l32;
        const int phys = (logi & 8) | ((logi ^ key) & 7);
        bf16x8 kf = *(const bf16x8*)(bK + key * 128 + phys * 8);
        sc[t] = __builtin_amdgcn_mfma_f32_32x32x16_bf16(qf[ks], kf, sc[t], 0, 0, 0);
      }
    }

    const bool diag = (k0 + 63 > qw);
    #pragma unroll
    for (int t = 0; t < 2; ++t) {
      const int col = t * 32 + l32;
      const int keyg = k0 + col;
      #pragma unroll
      for (int r = 0; r < 16; ++r) {
        const int rl = (r & 3) + 8 * (r >> 2) + 4 * half;
        float v = sc[t][r] * scale;
        if (diag && (keyg > qw + rl)) v = -1e30f;
        sPw[rl * 64 + (((col >> 3) ^ (rl & 7)) * 8) + (col & 7)] = f2bf(__expf(v));
      }
    }

    #pragma unroll
    for (int ksp = 0; ksp < 4; ++ksp) {
      const int logi = ksp * 2 + half;
      bf16x8 pf = *(const bf16x8*)(sPw + l32 * 64 + ((logi ^ (l32 & 7)) * 8));
      l_acc = __builtin_amdgcn_mfma_f32_32x32x16_bf16(pf, ones, l_acc, 0, 0, 0);
      #pragma unroll
      for (int ft = 0; ft < 4; ++ft) {
        const int feat = ft * 32 + l32;
        const int phys = logi ^ (feat & 7);
        bf16x8 vf = *(const bf16x8*)(bV + feat * 64 + phys * 8);
        Oacc[ft] = __builtin_amdgcn_mfma_f32_32x32x16_bf16(pf, vf, Oacc[ft], 0, 0, 0);
      }
    }
  }

  #pragma unroll
  for (int ft = 0; ft < 4; ++ft) {
    const int feat = ft * 32 + l32;
    #pragma unroll
    for (int r = 0; r < 16; ++r) {
      const int rl = (r & 3) + 8 * (r >> 2) + 4 * half;
      Og[(size_t)(qw + rl) * D_ + feat] = f2bf(Oacc[ft][r] / l_acc[r]);
    }
  }
}

// ---------------- launch ----------------
extern "C" void kernel_launch(void* const* d_in, const int* in_sizes, int n_in,
                              void* d_out, int out_size, void* d_ws, size_t ws_size,
                              hipStream_t stream) {
  const float* x  = (const float*)d_in[0];
  const float* Wq = (const float*)d_in[1];
  const float* Wk = (const float*)d_in[2];
  const float* Wv = (const float*)d_in[3];
  const float* Wo = (const float*)d_in[4];
  const int*  pos = (const int*)d_in[5];
  float* out = (float*)d_out;

  char* ws = (char*)d_ws;
  size_t off = 0;
  auto alloc = [&](size_t bytes) { void* p = ws + off; off += (bytes + 255) & ~255ULL; return p; };
  const size_t nx = (size_t)M_ * D_;
  const size_t nw = (size_t)D_ * D_;
  unsigned short* xb  = (unsigned short*)alloc(nx * 2);
  unsigned short* wqb = (unsigned short*)alloc(nw * 2);
  unsigned short* wkb = (unsigned short*)alloc(nw * 2);
  unsigned short* wvb = (unsigned short*)alloc(nw * 2);
  unsigned short* wob = (unsigned short*)alloc(nw * 2);
  unsigned short* Qb  = (unsigned short*)alloc(nx * 2);
  unsigned short* Kb  = (unsigned short*)alloc(nx * 2);
  unsigned short* Vb  = (unsigned short*)alloc(nx * 2);
  unsigned short* AOb = xb;   // alias: x_bf16 dead after QKV projection
  unsigned short* VTb = wqb;  // alias: Wq/Wk bf16 dead after QKV projection

  hipLaunchKernelGGL(cvt_bf16, dim3(nx / 1024), dim3(256), 0, stream, x,  xb,  (int)nx);
  hipLaunchKernelGGL(cvt_bf16, dim3(nw / 1024), dim3(256), 0, stream, Wq, wqb, (int)nw);
  hipLaunchKernelGGL(cvt_bf16, dim3(nw / 1024), dim3(256), 0, stream, Wk, wkb, (int)nw);
  hipLaunchKernelGGL(cvt_bf16, dim3(nw / 1024), dim3(256), 0, stream, Wv, wvb, (int)nw);
  hipLaunchKernelGGL(cvt_bf16, dim3(nw / 1024), dim3(256), 0, stream, Wo, wob, (int)nw);

  // fused QKV projection: 256^2 8-phase, grid.z = 3
  hipLaunchKernelGGL((gemm8p<1>), dim3(D_ / 256, M_ / 256, 3), dim3(512), 0, stream,
                     xb, wqb, wkb, wvb, (void*)Qb, (void*)Kb, (void*)Vb, M_, D_, D_);

  hipLaunchKernelGGL(rope_kernel, dim3((B_ * S_ * H_ * 64) / 256), dim3(256), 0, stream, Qb, Kb, pos);

  // V -> VT (per-b 2048x2048 transpose), into dead Wq/Wk bf16 space
  hipLaunchKernelGGL(transpose_bf16, dim3(1024, 2), dim3(256), 0, stream, Vb, VTb);

  hipLaunchKernelGGL(flash_attn, dim3(B_ * H_ * (S_ / 128)), dim3(256), 0, stream, Qb, Kb, VTb, AOb);

  hipLaunchKernelGGL((gemm8p<0>), dim3(D_ / 256, M_ / 256, 1), dim3(512), 0, stream,
                     AOb, wob, wob, wob, (void*)out, (void*)out, (void*)out, M_, D_, D_);
}

// Round 3
// 447.712 us; speedup vs baseline: 1.0266x; 1.0180x over previous
//
#include <hip/hip_runtime.h>
#include <hip/hip_bf16.h>
#include <cstdint>
#include <cstddef>

#define B_ 2
#define S_ 2048
#define D_ 2048
#define H_ 16
#define DK_ 128
#define M_ (B_*S_)   // 4096

typedef __attribute__((ext_vector_type(8))) __bf16 bf16x8;
typedef __attribute__((ext_vector_type(4))) float f32x4;
typedef __attribute__((ext_vector_type(16))) float f32x16;

__device__ __forceinline__ unsigned short f2bf(float f) {
  union { float f; unsigned int u; } v; v.f = f;
  unsigned int r = (v.u + 0x7fffu + ((v.u >> 16) & 1u)) >> 16;
  return (unsigned short)r;
}
__device__ __forceinline__ float bf2f(unsigned short b) {
  union { unsigned int u; float f; } v; v.u = ((unsigned int)b) << 16;
  return v.f;
}

// async global->LDS, 16B per lane; LDS dest is wave-uniform base + lane*16
__device__ __forceinline__ void gld16(const void* g, void* l) {
  __builtin_amdgcn_global_load_lds(
      (const __attribute__((address_space(1))) unsigned int*)g,
      (__attribute__((address_space(3))) unsigned int*)l, 16, 0, 0);
}

// ---------------- fp32 -> bf16 ----------------
__global__ void cvt_bf16(const float* __restrict__ src, unsigned short* __restrict__ dst, int n) {
  int i = (blockIdx.x * blockDim.x + threadIdx.x) * 4;
  if (i + 3 < n) {
    float4 v = *(const float4*)(src + i);
    dst[i+0] = f2bf(v.x); dst[i+1] = f2bf(v.y);
    dst[i+2] = f2bf(v.z); dst[i+3] = f2bf(v.w);
  }
}

// ---------------- 256x256 8-phase GEMM: C(MxN) = A(MxK) * Bt(NxK)^T ----------------
// 512 threads = 8 waves (2M x 4N), BK=64 as two K-halves of 32, 2 LDS bufs (128 KiB).
// Per phase: ds_read subtile || stage 1 half-tile (2x global_load_lds) -> barrier ->
// lgkmcnt(0) -> setprio(1) + 16 MFMA -> barrier. Counted vmcnt(4) once per K-tile.
template<int WRITE_BF16>
__global__ __launch_bounds__(512, 2) void gemm8p(const unsigned short* __restrict__ A,
                                                 const unsigned short* __restrict__ W0,
                                                 const unsigned short* __restrict__ W1,
                                                 const unsigned short* __restrict__ W2,
                                                 void* __restrict__ C0, void* __restrict__ C1,
                                                 void* __restrict__ C2,
                                                 int M, int N, int K) {
  __shared__ unsigned short sA[2][2][256 * 32];   // [buf][khalf][256 rows x 32 k] 16KB each
  __shared__ unsigned short sB[2][2][256 * 32];
  const int z = blockIdx.z;
  const unsigned short* Bt = (z == 0) ? W0 : (z == 1) ? W1 : W2;
  void* Cout = (z == 0) ? C0 : (z == 1) ? C1 : C2;

  const int tid  = threadIdx.x;
  const int lane = tid & 63;
  const int wid  = tid >> 6;
  const int wm = wid >> 2, wn = wid & 3;           // wave tile: rows wm*128, cols wn*64
  const int l16 = lane & 15, quad = lane >> 4;
  const int col16 = quad ^ ((lane >> 1) & 3);      // swizzled 16B chunk for frag reads
  const int qk_log = (lane & 3) ^ ((lane >> 3) & 3); // inverse swizzle for staging source
  const int srow = lane >> 2;                      // staging row within 16-row group
  const int bm = blockIdx.y * 256, bn = blockIdx.x * 256;
  const int NT = K >> 6;                           // K-tiles of 64

  f32x4 acc[8][4];
  #pragma unroll
  for (int i = 0; i < 8; ++i)
    #pragma unroll
    for (int j = 0; j < 4; ++j)
      acc[i][j] = (f32x4){0.f, 0.f, 0.f, 0.f};

  auto stage = [&](const unsigned short* __restrict__ g, int rowbase,
                   unsigned short* l, int t, int kh) {
    const unsigned short* src = g + (size_t)rowbase * K + t * 64 + kh * 32 + qk_log * 8;
    #pragma unroll
    for (int p = 0; p < 2; ++p) {
      const int i = wid * 2 + p;                   // issue 0..15, 16 rows each
      gld16(src + (size_t)(i * 16 + srow) * K, l + i * 512);
    }
  };

  // prologue: tile0 fully, tile1 kh0; wait tile0 (leave 4 loads in flight)
  stage(A,  bm, &sA[0][0][0], 0, 0);
  stage(Bt, bn, &sB[0][0][0], 0, 0);
  stage(A,  bm, &sA[0][1][0], 0, 1);
  stage(Bt, bn, &sB[0][1][0], 0, 1);
  stage(A,  bm, &sA[1][0][0], 1, 0);
  stage(Bt, bn, &sB[1][0][0], 1, 0);
  asm volatile("s_waitcnt vmcnt(4)" ::: "memory");
  __builtin_amdgcn_s_barrier();

  for (int t = 0; t < NT; ++t) {
    const int buf = t & 1;
    bf16x8 bfrag[4];                               // B frags persist across mh phases
    #pragma unroll
    for (int ph = 0; ph < 4; ++ph) {
      const int ks = ph >> 1;                      // K-half consumed this phase
      const int mh = ph & 1;                       // wave-tile M-half this phase
      bf16x8 afrag[4];
      const unsigned short* aP = &sA[buf][ks][0] +
          (size_t)((wm * 128 + mh * 64 + l16) * 4 + col16) * 8;
      #pragma unroll
      for (int mf = 0; mf < 4; ++mf)
        afrag[mf] = *(const bf16x8*)(aP + mf * 512);
      if (mh == 0) {
        const unsigned short* bP = &sB[buf][ks][0] +
            (size_t)((wn * 64 + l16) * 4 + col16) * 8;
        #pragma unroll
        for (int nf = 0; nf < 4; ++nf)
          bfrag[nf] = *(const bf16x8*)(bP + nf * 512);
      }
      if (ph == 0)      { if (t + 1 < NT) stage(A,  bm, &sA[buf ^ 1][1][0], t + 1, 1); }
      else if (ph == 1) { if (t + 1 < NT) stage(Bt, bn, &sB[buf ^ 1][1][0], t + 1, 1); }
      else if (ph == 2) { if (t + 2 < NT) stage(A,  bm, &sA[buf][0][0],     t + 2, 0); }
      else              { if (t + 2 < NT) stage(Bt, bn, &sB[buf][0][0],     t + 2, 0); }

      __builtin_amdgcn_s_barrier();
      asm volatile("s_waitcnt lgkmcnt(0)" ::: "memory");
      __builtin_amdgcn_s_setprio(1);
      #pragma unroll
      for (int nf = 0; nf < 4; ++nf)
        #pragma unroll
        for (int mf = 0; mf < 4; ++mf)
          acc[mh * 4 + mf][nf] = __builtin_amdgcn_mfma_f32_16x16x32_bf16(
              afrag[mf], bfrag[nf], acc[mh * 4 + mf][nf], 0, 0, 0);
      __builtin_amdgcn_s_setprio(0);
      if (ph == 3) {  // once per K-tile: counted wait
        if (t + 2 < NT) asm volatile("s_waitcnt vmcnt(4)" ::: "memory");
        else            asm volatile("s_waitcnt vmcnt(0)" ::: "memory");
      }
      __builtin_amdgcn_s_barrier();
    }
  }

  #pragma unroll
  for (int mf = 0; mf < 8; ++mf) {
    const int row = bm + wm * 128 + mf * 16 + quad * 4;
    #pragma unroll
    for (int nf = 0; nf < 4; ++nf) {
      const int col = bn + wn * 64 + nf * 16 + l16;
      #pragma unroll
      for (int r = 0; r < 4; ++r) {
        if (WRITE_BF16)
          ((unsigned short*)Cout)[(size_t)(row + r) * N + col] = f2bf(acc[mf][nf][r]);
        else
          ((float*)Cout)[(size_t)(row + r) * N + col] = acc[mf][nf][r];
      }
    }
  }
}

// ---------------- 128x128 m97-style GEMM (for half-machine shapes: out-proj) ----------------
template<int WRITE_BF16>
__global__ __launch_bounds__(256) void gemm_bt(const unsigned short* __restrict__ A,
                                               const unsigned short* __restrict__ W0,
                                               const unsigned short* __restrict__ W1,
                                               const unsigned short* __restrict__ W2,
                                               void* __restrict__ C0, void* __restrict__ C1,
                                               void* __restrict__ C2,
                                               int M, int N, int K) {
  __shared__ unsigned short sA[128 * 32];
  __shared__ unsigned short sB[128 * 32];
  const int z = blockIdx.z;
  const unsigned short* Bt = (z == 0) ? W0 : (z == 1) ? W1 : W2;
  void* Cout = (z == 0) ? C0 : (z == 1) ? C1 : C2;

  const int tid  = threadIdx.x;
  const int lane = tid & 63;
  const int wid  = tid >> 6;
  const int wm = wid >> 1, wn = wid & 1;
  const int quad = lane >> 4, l16 = lane & 15;
  const int bm = blockIdx.y * 128, bn = blockIdx.x * 128;
  const int srow = lane >> 2;          // 0..15
  const int scol = (lane & 3) * 8;     // 0,8,16,24

  f32x4 acc[4][4];
  #pragma unroll
  for (int i = 0; i < 4; ++i)
    #pragma unroll
    for (int j = 0; j < 4; ++j)
      acc[i][j] = (f32x4){0.f, 0.f, 0.f, 0.f};

  for (int k0 = 0; k0 < K; k0 += 32) {
    __syncthreads();
    #pragma unroll
    for (int p = 0; p < 2; ++p) {
      int row = p * 64 + wid * 16;
      gld16(A  + (size_t)(bm + row + srow) * K + k0 + scol, sA + row * 32);
      gld16(Bt + (size_t)(bn + row + srow) * K + k0 + scol, sB + row * 32);
    }
    __syncthreads();

    bf16x8 af[4], bfr[4];
    #pragma unroll
    for (int i = 0; i < 4; ++i)
      af[i] = *(const bf16x8*)(sA + (wm * 64 + i * 16 + l16) * 32 + quad * 8);
    #pragma unroll
    for (int j = 0; j < 4; ++j)
      bfr[j] = *(const bf16x8*)(sB + (wn * 64 + j * 16 + l16) * 32 + quad * 8);
    #pragma unroll
    for (int i = 0; i < 4; ++i)
      #pragma unroll
      for (int j = 0; j < 4; ++j)
        acc[i][j] = __builtin_amdgcn_mfma_f32_16x16x32_bf16(af[i], bfr[j], acc[i][j], 0, 0, 0);
  }

  #pragma unroll
  for (int i = 0; i < 4; ++i) {
    int row = bm + wm * 64 + i * 16 + quad * 4;
    #pragma unroll
    for (int j = 0; j < 4; ++j) {
      int col = bn + wn * 64 + j * 16 + l16;
      #pragma unroll
      for (int r = 0; r < 4; ++r) {
        if (WRITE_BF16)
          ((unsigned short*)Cout)[(size_t)(row + r) * N + col] = f2bf(acc[i][j][r]);
        else
          ((float*)Cout)[(size_t)(row + r) * N + col] = acc[i][j][r];
      }
    }
  }
}

// ---------------- RoPE (in-place on bf16 Q and K) ----------------
__global__ void rope_kernel(unsigned short* __restrict__ Q, unsigned short* __restrict__ K,
                            const int* __restrict__ pos) {
  int idx = blockIdx.x * blockDim.x + threadIdx.x;
  int i = idx & 63;
  int h = (idx >> 6) & (H_ - 1);
  int s = (idx >> 10) & (S_ - 1);
  int b = idx >> 21;
  float p = (float)pos[s];
  float inv = expf(-(float)i * (9.210340371976184f / 64.0f));
  float ang = p * inv;
  float sn, cs;
  sincosf(ang, &sn, &cs);
  size_t base = (((size_t)b * S_ + s) * D_) + (size_t)h * DK_ + 2 * i;
  float x1 = bf2f(Q[base]), x2 = bf2f(Q[base + 1]);
  Q[base]     = f2bf(x1 * cs - x2 * sn);
  Q[base + 1] = f2bf(x1 * sn + x2 * cs);
  x1 = bf2f(K[base]); x2 = bf2f(K[base + 1]);
  K[base]     = f2bf(x1 * cs - x2 * sn);
  K[base + 1] = f2bf(x1 * sn + x2 * cs);
}

// ---------------- V transpose: per b, VT[col][m] = V[m][col] ----------------
__global__ __launch_bounds__(256) void transpose_bf16(const unsigned short* __restrict__ src,
                                                      unsigned short* __restrict__ dst) {
  __shared__ unsigned short sT[64 * 64];
  const int b = blockIdx.y;
  const int tx = blockIdx.x & 31, ty = blockIdx.x >> 5;
  const size_t base = (size_t)b * 2048 * 2048;
  const int m0 = ty * 64, c0 = tx * 64;
  const int tid = threadIdx.x;
  #pragma unroll
  for (int c = 0; c < 2; ++c) {
    int idx = tid + c * 256;
    int row = idx >> 3;               // 0..63 (m)
    int chk = idx & 7;                // col chunk
    uint4 v = *(const uint4*)(src + base + (size_t)(m0 + row) * 2048 + c0 + chk * 8);
    *(uint4*)(sT + row * 64 + ((chk ^ (row & 7)) * 8)) = v;
  }
  __syncthreads();
  #pragma unroll
  for (int c = 0; c < 2; ++c) {
    int idx = tid + c * 256;
    int orow = idx >> 3;              // output row = col index
    int ocol = (idx & 7) * 8;         // output col = m index
    unsigned short tmp[8];
    #pragma unroll
    for (int j = 0; j < 8; ++j) {
      int lr = ocol + j;              // logical row (m)
      int lc = orow;                  // logical col
      tmp[j] = sT[lr * 64 + (((lc >> 3) ^ (lr & 7)) * 8) + (lc & 7)];
    }
    *(uint4*)(dst + base + (size_t)(c0 + orow) * 2048 + m0 + ocol) = *(const uint4*)tmp;
  }
}

// ---------------- Flash attention (causal), 32x32 MFMA, pipelined staging ----------------
// Load-balance: co-resident block pair (x, x+256) gets complementary causal depth
// (qi, 15-qi) so every CU does 34 k-tile-iters regardless of placement.
__global__ __launch_bounds__(256, 2) void flash_attn(const unsigned short* __restrict__ Q,
                                                     const unsigned short* __restrict__ K,
                                                     const unsigned short* __restrict__ VT,
                                                     unsigned short* __restrict__ O) {
  __shared__ unsigned short sK[2][64 * 128];   // [buf][key][feat-chunk swz] 16KB each
  __shared__ unsigned short sVT[2][128 * 64];  // [buf][feat][key-chunk swz] 16KB each
  __shared__ unsigned short sP[4][32 * 64];    // per-wave 32x64 P, swz, 4KB each

  const int tid = threadIdx.x, lane = tid & 63, wid = tid >> 6;
  const int half = lane >> 5, l32 = lane & 31;
  const int x = blockIdx.x;
  const int j = x & 15;
  const int bh = x >> 4;                        // 0..31 (b*16+h)
  const int qi = (x < 256) ? (15 - j) : j;      // complementary across +256 co-residency
  const int h = bh & (H_ - 1), b = bh >> 4;
  const int qw = qi * 128 + wid * 32;          // this wave's first Q row
  const size_t qkbase = ((size_t)b * S_) * D_ + (size_t)h * DK_;
  const unsigned short* Qg = Q + qkbase;
  const unsigned short* Kg = K + qkbase;
  const unsigned short* VTg = VT + (size_t)bh * DK_ * S_;   // [dk][s]
  unsigned short* Og = O + qkbase;
  unsigned short* sPw = sP[wid];

  const int kKeySub = lane >> 4;               // K: 4 key rows per issue
  const int kPhys   = lane & 15;               // 16 chunks per 256B K row
  const int vFeatSub = lane >> 3;              // VT: 8 feat rows per issue
  const int vPhys    = lane & 7;               // 8 chunks per 128B VT row

  bf16x8 qf[8];
  #pragma unroll
  for (int ks = 0; ks < 8; ++ks)
    qf[ks] = *(const bf16x8*)(Qg + (size_t)(qw + l32) * D_ + ks * 16 + half * 8);

  union { unsigned short u[8]; bf16x8 v; } onesu;
  #pragma unroll
  for (int j2 = 0; j2 < 8; ++j2) onesu.u[j2] = 0x3F80;  // bf16 1.0
  const bf16x8 ones = onesu.v;

  f32x16 Oacc[4];
  #pragma unroll
  for (int ft = 0; ft < 4; ++ft)
    #pragma unroll
    for (int r = 0; r < 16; ++r) Oacc[ft][r] = 0.f;
  f32x16 l_acc;
  #pragma unroll
  for (int r = 0; r < 16; ++r) l_acc[r] = 0.f;
  const float scale = 0.08838834764831845f;    // 1/sqrt(128)

  const int nkb = 2 * (qi + 1);

  auto stage = [&](int kb) {
    const int k0 = kb * 64;
    unsigned short* bK = sK[kb & 1];
    unsigned short* bV = sVT[kb & 1];
    #pragma unroll
    for (int p = 0; p < 4; ++p) {
      int issue = wid * 4 + p;                 // 0..15
      int key = issue * 4 + kKeySub;
      int logiK = (kPhys & 8) | ((kPhys ^ key) & 7);
      gld16(Kg + (size_t)(k0 + key) * D_ + logiK * 8, bK + issue * 512);
      int feat = issue * 8 + vFeatSub;
      int logiV = vPhys ^ (feat & 7);
      gld16(VTg + (size_t)feat * S_ + k0 + logiV * 8, bV + issue * 512);
    }
  };

  stage(0);

  for (int kb = 0; kb < nkb; ++kb) {
    __syncthreads();   // drains vmcnt: buf[kb&1] ready; prior reads of other buf done
    if (kb + 1 < nkb) stage(kb + 1);

    const int k0 = kb * 64;
    if (k0 > qw + 31) continue;                // fully-masked for this wave (uniform)

    const unsigned short* bK = sK[kb & 1];
    const unsigned short* bV = sVT[kb & 1];

    f32x16 sc[2];
    #pragma unroll
    for (int t = 0; t < 2; ++t)
      #pragma unroll
      for (int r = 0; r < 16; ++r) sc[t][r] = 0.f;
    #pragma unroll
    for (int ks = 0; ks < 8; ++ks) {
      const int logi = ks * 2 + half;
      #pragma unroll
      for (int t = 0; t < 2; ++t) {
        const int key = t * 32 + l32;
        const int phys = (logi & 8) | ((logi ^ key) & 7);
        bf16x8 kf = *(const bf16x8*)(bK + key * 128 + phys * 8);
        sc[t] = __builtin_amdgcn_mfma_f32_32x32x16_bf16(qf[ks], kf, sc[t], 0, 0, 0);
      }
    }

    const bool diag = (k0 + 63 > qw);
    #pragma unroll
    for (int t = 0; t < 2; ++t) {
      const int col = t * 32 + l32;
      const int keyg = k0 + col;
      #pragma unroll
      for (int r = 0; r < 16; ++r) {
        const int rl = (r & 3) + 8 * (r >> 2) + 4 * half;
        float v = sc[t][r] * scale;
        if (diag && (keyg > qw + rl)) v = -1e30f;
        sPw[rl * 64 + (((col >> 3) ^ (rl & 7)) * 8) + (col & 7)] = f2bf(__expf(v));
      }
    }

    #pragma unroll
    for (int ksp = 0; ksp < 4; ++ksp) {
      const int logi = ksp * 2 + half;
      bf16x8 pf = *(const bf16x8*)(sPw + l32 * 64 + ((logi ^ (l32 & 7)) * 8));
      l_acc = __builtin_amdgcn_mfma_f32_32x32x16_bf16(pf, ones, l_acc, 0, 0, 0);
      #pragma unroll
      for (int ft = 0; ft < 4; ++ft) {
        const int feat = ft * 32 + l32;
        const int phys = logi ^ (feat & 7);
        bf16x8 vf = *(const bf16x8*)(bV + feat * 64 + phys * 8);
        Oacc[ft] = __builtin_amdgcn_mfma_f32_32x32x16_bf16(pf, vf, Oacc[ft], 0, 0, 0);
      }
    }
  }

  #pragma unroll
  for (int ft = 0; ft < 4; ++ft) {
    const int feat = ft * 32 + l32;
    #pragma unroll
    for (int r = 0; r < 16; ++r) {
      const int rl = (r & 3) + 8 * (r >> 2) + 4 * half;
      Og[(size_t)(qw + rl) * D_ + feat] = f2bf(Oacc[ft][r] / l_acc[r]);
    }
  }
}

// ---------------- launch ----------------
extern "C" void kernel_launch(void* const* d_in, const int* in_sizes, int n_in,
                              void* d_out, int out_size, void* d_ws, size_t ws_size,
                              hipStream_t stream) {
  const float* x  = (const float*)d_in[0];
  const float* Wq = (const float*)d_in[1];
  const float* Wk = (const float*)d_in[2];
  const float* Wv = (const float*)d_in[3];
  const float* Wo = (const float*)d_in[4];
  const int*  pos = (const int*)d_in[5];
  float* out = (float*)d_out;

  char* ws = (char*)d_ws;
  size_t off = 0;
  auto alloc = [&](size_t bytes) { void* p = ws + off; off += (bytes + 255) & ~255ULL; return p; };
  const size_t nx = (size_t)M_ * D_;
  const size_t nw = (size_t)D_ * D_;
  unsigned short* xb  = (unsigned short*)alloc(nx * 2);
  unsigned short* wqb = (unsigned short*)alloc(nw * 2);
  unsigned short* wkb = (unsigned short*)alloc(nw * 2);
  unsigned short* wvb = (unsigned short*)alloc(nw * 2);
  unsigned short* wob = (unsigned short*)alloc(nw * 2);
  unsigned short* Qb  = (unsigned short*)alloc(nx * 2);
  unsigned short* Kb  = (unsigned short*)alloc(nx * 2);
  unsigned short* Vb  = (unsigned short*)alloc(nx * 2);
  unsigned short* AOb = xb;   // alias: x_bf16 dead after QKV projection
  unsigned short* VTb = wqb;  // alias: Wq/Wk bf16 dead after QKV projection

  hipLaunchKernelGGL(cvt_bf16, dim3(nx / 1024), dim3(256), 0, stream, x,  xb,  (int)nx);
  hipLaunchKernelGGL(cvt_bf16, dim3(nw / 1024), dim3(256), 0, stream, Wq, wqb, (int)nw);
  hipLaunchKernelGGL(cvt_bf16, dim3(nw / 1024), dim3(256), 0, stream, Wk, wkb, (int)nw);
  hipLaunchKernelGGL(cvt_bf16, dim3(nw / 1024), dim3(256), 0, stream, Wv, wvb, (int)nw);
  hipLaunchKernelGGL(cvt_bf16, dim3(nw / 1024), dim3(256), 0, stream, Wo, wob, (int)nw);

  // fused QKV projection: 256^2 8-phase, grid.z = 3
  hipLaunchKernelGGL((gemm8p<1>), dim3(D_ / 256, M_ / 256, 3), dim3(512), 0, stream,
                     xb, wqb, wkb, wvb, (void*)Qb, (void*)Kb, (void*)Vb, M_, D_, D_);

  hipLaunchKernelGGL(rope_kernel, dim3((B_ * S_ * H_ * 64) / 256), dim3(256), 0, stream, Qb, Kb, pos);

  // V -> VT (per-b 2048x2048 transpose), into dead Wq/Wk bf16 space
  hipLaunchKernelGGL(transpose_bf16, dim3(1024, 2), dim3(256), 0, stream, Vb, VTb);

  hipLaunchKernelGGL(flash_attn, dim3(B_ * H_ * (S_ / 128)), dim3(256), 0, stream, Qb, Kb, VTb, AOb);

  // out-projection: 128^2 m97-style (512 blocks = 2 exact full-machine rounds)
  hipLaunchKernelGGL((gemm_bt<0>), dim3(D_ / 128, M_ / 128, 1), dim3(256), 0, stream,
                     AOb, wob, wob, wob, (void*)out, (void*)out, (void*)out, M_, D_, D_);
}

// Round 4
// 438.509 us; speedup vs baseline: 1.0481x; 1.0210x over previous
//
#include <hip/hip_runtime.h>
#include <hip/hip_bf16.h>
#include <cstdint>
#include <cstddef>

#define B_ 2
#define S_ 2048
#define D_ 2048
#define H_ 16
#define DK_ 128
#define M_ (B_*S_)   // 4096

typedef __attribute__((ext_vector_type(8))) __bf16 bf16x8;
typedef __attribute__((ext_vector_type(4))) float f32x4;
typedef __attribute__((ext_vector_type(16))) float f32x16;

__device__ __forceinline__ unsigned short f2bf(float f) {
  union { float f; unsigned int u; } v; v.f = f;
  unsigned int r = (v.u + 0x7fffu + ((v.u >> 16) & 1u)) >> 16;
  return (unsigned short)r;
}
__device__ __forceinline__ float bf2f(unsigned short b) {
  union { unsigned int u; float f; } v; v.u = ((unsigned int)b) << 16;
  return v.f;
}

// async global->LDS, 16B per lane; LDS dest is wave-uniform base + lane*16
__device__ __forceinline__ void gld16(const void* g, void* l) {
  __builtin_amdgcn_global_load_lds(
      (const __attribute__((address_space(1))) unsigned int*)g,
      (__attribute__((address_space(3))) unsigned int*)l, 16, 0, 0);
}

// ---------------- fused fp32 -> bf16 for x|Wq|Wk|Wv|Wo (contiguous dst) ----------------
// nx = 2^23, nw = 2^22; dst regions are contiguous in workspace.
__global__ void cvt_all(const float* __restrict__ x,  const float* __restrict__ Wq,
                        const float* __restrict__ Wk, const float* __restrict__ Wv,
                        const float* __restrict__ Wo, unsigned short* __restrict__ dst) {
  size_t i = ((size_t)blockIdx.x * blockDim.x + threadIdx.x) * 4;
  const float* src;
  size_t off;
  if (i < ((size_t)M_ * D_)) {            // x region (2^23)
    src = x; off = i;
  } else {
    size_t j = i - (size_t)M_ * D_;
    int w = (int)(j >> 22);               // nw = 2^22
    off = j & ((1u << 22) - 1);
    src = (w == 0) ? Wq : (w == 1) ? Wk : (w == 2) ? Wv : Wo;
  }
  float4 v = *(const float4*)(src + off);
  dst[i+0] = f2bf(v.x); dst[i+1] = f2bf(v.y);
  dst[i+2] = f2bf(v.z); dst[i+3] = f2bf(v.w);
}

// ---------------- 256x256 8-phase GEMM: C(MxN) = A(MxK) * Bt(NxK)^T ----------------
// 512 threads = 8 waves (2M x 4N), BK=64 as two K-halves of 32, 2 LDS bufs (128 KiB).
// Per phase: ds_read subtile || stage 1 half-tile (2x global_load_lds) -> barrier ->
// lgkmcnt(0) -> setprio(1) + 16 MFMA -> barrier. Counted vmcnt(4) once per K-tile.
template<int WRITE_BF16>
__global__ __launch_bounds__(512, 2) void gemm8p(const unsigned short* __restrict__ A,
                                                 const unsigned short* __restrict__ W0,
                                                 const unsigned short* __restrict__ W1,
                                                 const unsigned short* __restrict__ W2,
                                                 void* __restrict__ C0, void* __restrict__ C1,
                                                 void* __restrict__ C2,
                                                 int M, int N, int K) {
  __shared__ unsigned short sA[2][2][256 * 32];   // [buf][khalf][256 rows x 32 k] 16KB each
  __shared__ unsigned short sB[2][2][256 * 32];
  const int z = blockIdx.z;
  const unsigned short* Bt = (z == 0) ? W0 : (z == 1) ? W1 : W2;
  void* Cout = (z == 0) ? C0 : (z == 1) ? C1 : C2;

  const int tid  = threadIdx.x;
  const int lane = tid & 63;
  const int wid  = tid >> 6;
  const int wm = wid >> 2, wn = wid & 3;           // wave tile: rows wm*128, cols wn*64
  const int l16 = lane & 15, quad = lane >> 4;
  const int col16 = quad ^ ((lane >> 1) & 3);      // swizzled 16B chunk for frag reads
  const int qk_log = (lane & 3) ^ ((lane >> 3) & 3); // inverse swizzle for staging source
  const int srow = lane >> 2;                      // staging row within 16-row group
  const int bm = blockIdx.y * 256, bn = blockIdx.x * 256;
  const int NT = K >> 6;                           // K-tiles of 64

  f32x4 acc[8][4];
  #pragma unroll
  for (int i = 0; i < 8; ++i)
    #pragma unroll
    for (int j = 0; j < 4; ++j)
      acc[i][j] = (f32x4){0.f, 0.f, 0.f, 0.f};

  auto stage = [&](const unsigned short* __restrict__ g, int rowbase,
                   unsigned short* l, int t, int kh) {
    const unsigned short* src = g + (size_t)rowbase * K + t * 64 + kh * 32 + qk_log * 8;
    #pragma unroll
    for (int p = 0; p < 2; ++p) {
      const int i = wid * 2 + p;                   // issue 0..15, 16 rows each
      gld16(src + (size_t)(i * 16 + srow) * K, l + i * 512);
    }
  };

  // prologue: tile0 fully, tile1 kh0; wait tile0 (leave 4 loads in flight)
  stage(A,  bm, &sA[0][0][0], 0, 0);
  stage(Bt, bn, &sB[0][0][0], 0, 0);
  stage(A,  bm, &sA[0][1][0], 0, 1);
  stage(Bt, bn, &sB[0][1][0], 0, 1);
  stage(A,  bm, &sA[1][0][0], 1, 0);
  stage(Bt, bn, &sB[1][0][0], 1, 0);
  asm volatile("s_waitcnt vmcnt(4)" ::: "memory");
  __builtin_amdgcn_s_barrier();

  for (int t = 0; t < NT; ++t) {
    const int buf = t & 1;
    bf16x8 bfrag[4];                               // B frags persist across mh phases
    #pragma unroll
    for (int ph = 0; ph < 4; ++ph) {
      const int ks = ph >> 1;                      // K-half consumed this phase
      const int mh = ph & 1;                       // wave-tile M-half this phase
      bf16x8 afrag[4];
      const unsigned short* aP = &sA[buf][ks][0] +
          (size_t)((wm * 128 + mh * 64 + l16) * 4 + col16) * 8;
      #pragma unroll
      for (int mf = 0; mf < 4; ++mf)
        afrag[mf] = *(const bf16x8*)(aP + mf * 512);
      if (mh == 0) {
        const unsigned short* bP = &sB[buf][ks][0] +
            (size_t)((wn * 64 + l16) * 4 + col16) * 8;
        #pragma unroll
        for (int nf = 0; nf < 4; ++nf)
          bfrag[nf] = *(const bf16x8*)(bP + nf * 512);
      }
      if (ph == 0)      { if (t + 1 < NT) stage(A,  bm, &sA[buf ^ 1][1][0], t + 1, 1); }
      else if (ph == 1) { if (t + 1 < NT) stage(Bt, bn, &sB[buf ^ 1][1][0], t + 1, 1); }
      else if (ph == 2) { if (t + 2 < NT) stage(A,  bm, &sA[buf][0][0],     t + 2, 0); }
      else              { if (t + 2 < NT) stage(Bt, bn, &sB[buf][0][0],     t + 2, 0); }

      __builtin_amdgcn_s_barrier();
      asm volatile("s_waitcnt lgkmcnt(0)" ::: "memory");
      __builtin_amdgcn_s_setprio(1);
      #pragma unroll
      for (int nf = 0; nf < 4; ++nf)
        #pragma unroll
        for (int mf = 0; mf < 4; ++mf)
          acc[mh * 4 + mf][nf] = __builtin_amdgcn_mfma_f32_16x16x32_bf16(
              afrag[mf], bfrag[nf], acc[mh * 4 + mf][nf], 0, 0, 0);
      __builtin_amdgcn_s_setprio(0);
      if (ph == 3) {  // once per K-tile: counted wait
        if (t + 2 < NT) asm volatile("s_waitcnt vmcnt(4)" ::: "memory");
        else            asm volatile("s_waitcnt vmcnt(0)" ::: "memory");
      }
      __builtin_amdgcn_s_barrier();
    }
  }

  #pragma unroll
  for (int mf = 0; mf < 8; ++mf) {
    const int row = bm + wm * 128 + mf * 16 + quad * 4;
    #pragma unroll
    for (int nf = 0; nf < 4; ++nf) {
      const int col = bn + wn * 64 + nf * 16 + l16;
      #pragma unroll
      for (int r = 0; r < 4; ++r) {
        if (WRITE_BF16)
          ((unsigned short*)Cout)[(size_t)(row + r) * N + col] = f2bf(acc[mf][nf][r]);
        else
          ((float*)Cout)[(size_t)(row + r) * N + col] = acc[mf][nf][r];
      }
    }
  }
}

// ---------------- 128x128 m97-style GEMM (for half-machine shapes: out-proj) ----------------
template<int WRITE_BF16>
__global__ __launch_bounds__(256) void gemm_bt(const unsigned short* __restrict__ A,
                                               const unsigned short* __restrict__ W0,
                                               const unsigned short* __restrict__ W1,
                                               const unsigned short* __restrict__ W2,
                                               void* __restrict__ C0, void* __restrict__ C1,
                                               void* __restrict__ C2,
                                               int M, int N, int K) {
  __shared__ unsigned short sA[128 * 32];
  __shared__ unsigned short sB[128 * 32];
  const int z = blockIdx.z;
  const unsigned short* Bt = (z == 0) ? W0 : (z == 1) ? W1 : W2;
  void* Cout = (z == 0) ? C0 : (z == 1) ? C1 : C2;

  const int tid  = threadIdx.x;
  const int lane = tid & 63;
  const int wid  = tid >> 6;
  const int wm = wid >> 1, wn = wid & 1;
  const int quad = lane >> 4, l16 = lane & 15;
  const int bm = blockIdx.y * 128, bn = blockIdx.x * 128;
  const int srow = lane >> 2;          // 0..15
  const int scol = (lane & 3) * 8;     // 0,8,16,24

  f32x4 acc[4][4];
  #pragma unroll
  for (int i = 0; i < 4; ++i)
    #pragma unroll
    for (int j = 0; j < 4; ++j)
      acc[i][j] = (f32x4){0.f, 0.f, 0.f, 0.f};

  for (int k0 = 0; k0 < K; k0 += 32) {
    __syncthreads();
    #pragma unroll
    for (int p = 0; p < 2; ++p) {
      int row = p * 64 + wid * 16;
      gld16(A  + (size_t)(bm + row + srow) * K + k0 + scol, sA + row * 32);
      gld16(Bt + (size_t)(bn + row + srow) * K + k0 + scol, sB + row * 32);
    }
    __syncthreads();

    bf16x8 af[4], bfr[4];
    #pragma unroll
    for (int i = 0; i < 4; ++i)
      af[i] = *(const bf16x8*)(sA + (wm * 64 + i * 16 + l16) * 32 + quad * 8);
    #pragma unroll
    for (int j = 0; j < 4; ++j)
      bfr[j] = *(const bf16x8*)(sB + (wn * 64 + j * 16 + l16) * 32 + quad * 8);
    #pragma unroll
    for (int i = 0; i < 4; ++i)
      #pragma unroll
      for (int j = 0; j < 4; ++j)
        acc[i][j] = __builtin_amdgcn_mfma_f32_16x16x32_bf16(af[i], bfr[j], acc[i][j], 0, 0, 0);
  }

  #pragma unroll
  for (int i = 0; i < 4; ++i) {
    int row = bm + wm * 64 + i * 16 + quad * 4;
    #pragma unroll
    for (int j = 0; j < 4; ++j) {
      int col = bn + wn * 64 + j * 16 + l16;
      #pragma unroll
      for (int r = 0; r < 4; ++r) {
        if (WRITE_BF16)
          ((unsigned short*)Cout)[(size_t)(row + r) * N + col] = f2bf(acc[i][j][r]);
        else
          ((float*)Cout)[(size_t)(row + r) * N + col] = acc[i][j][r];
      }
    }
  }
}

// ---------------- RoPE (in-place on bf16 Q and K) ----------------
__global__ void rope_kernel(unsigned short* __restrict__ Q, unsigned short* __restrict__ K,
                            const int* __restrict__ pos) {
  int idx = blockIdx.x * blockDim.x + threadIdx.x;
  int i = idx & 63;
  int h = (idx >> 6) & (H_ - 1);
  int s = (idx >> 10) & (S_ - 1);
  int b = idx >> 21;
  float p = (float)pos[s];
  float inv = expf(-(float)i * (9.210340371976184f / 64.0f));
  float ang = p * inv;
  float sn, cs;
  sincosf(ang, &sn, &cs);
  size_t base = (((size_t)b * S_ + s) * D_) + (size_t)h * DK_ + 2 * i;
  float x1 = bf2f(Q[base]), x2 = bf2f(Q[base + 1]);
  Q[base]     = f2bf(x1 * cs - x2 * sn);
  Q[base + 1] = f2bf(x1 * sn + x2 * cs);
  x1 = bf2f(K[base]); x2 = bf2f(K[base + 1]);
  K[base]     = f2bf(x1 * cs - x2 * sn);
  K[base + 1] = f2bf(x1 * sn + x2 * cs);
}

// ---------------- V transpose: per b, VT[col][m] = V[m][col] ----------------
__global__ __launch_bounds__(256) void transpose_bf16(const unsigned short* __restrict__ src,
                                                      unsigned short* __restrict__ dst) {
  __shared__ unsigned short sT[64 * 64];
  const int b = blockIdx.y;
  const int tx = blockIdx.x & 31, ty = blockIdx.x >> 5;
  const size_t base = (size_t)b * 2048 * 2048;
  const int m0 = ty * 64, c0 = tx * 64;
  const int tid = threadIdx.x;
  #pragma unroll
  for (int c = 0; c < 2; ++c) {
    int idx = tid + c * 256;
    int row = idx >> 3;               // 0..63 (m)
    int chk = idx & 7;                // col chunk
    uint4 v = *(const uint4*)(src + base + (size_t)(m0 + row) * 2048 + c0 + chk * 8);
    *(uint4*)(sT + row * 64 + ((chk ^ (row & 7)) * 8)) = v;
  }
  __syncthreads();
  #pragma unroll
  for (int c = 0; c < 2; ++c) {
    int idx = tid + c * 256;
    int orow = idx >> 3;              // output row = col index
    int ocol = (idx & 7) * 8;         // output col = m index
    unsigned short tmp[8];
    #pragma unroll
    for (int j = 0; j < 8; ++j) {
      int lr = ocol + j;              // logical row (m)
      int lc = orow;                  // logical col
      tmp[j] = sT[lr * 64 + (((lc >> 3) ^ (lr & 7)) * 8) + (lc & 7)];
    }
    *(uint4*)(dst + base + (size_t)(c0 + orow) * 2048 + m0 + ocol) = *(const uint4*)tmp;
  }
}

// ---------------- Flash attention (causal), 32x32 MFMA, pipelined staging ----------------
// Ordering: heavy-first within each bh group (qi = 15-j) -> light blocks dispatched last,
// greedy refill keeps CUs fed and the tail is shallow. (Round-1 pairing regressed: it put
// the heaviest blocks last.)
__global__ __launch_bounds__(256, 2) void flash_attn(const unsigned short* __restrict__ Q,
                                                     const unsigned short* __restrict__ K,
                                                     const unsigned short* __restrict__ VT,
                                                     unsigned short* __restrict__ O) {
  __shared__ unsigned short sK[2][64 * 128];   // [buf][key][feat-chunk swz] 16KB each
  __shared__ unsigned short sVT[2][128 * 64];  // [buf][feat][key-chunk swz] 16KB each
  __shared__ unsigned short sP[4][32 * 64];    // per-wave 32x64 P, swz, 4KB each

  const int tid = threadIdx.x, lane = tid & 63, wid = tid >> 6;
  const int half = lane >> 5, l32 = lane & 31;
  const int qi = 15 - (blockIdx.x & 15);       // 16 q-blocks of 128 rows; heavy first
  const int bh = blockIdx.x >> 4;
  const int h = bh & (H_ - 1), b = bh >> 4;
  const int qw = qi * 128 + wid * 32;          // this wave's first Q row
  const size_t qkbase = ((size_t)b * S_) * D_ + (size_t)h * DK_;
  const unsigned short* Qg = Q + qkbase;
  const unsigned short* Kg = K + qkbase;
  const unsigned short* VTg = VT + (size_t)bh * DK_ * S_;   // [dk][s]
  unsigned short* Og = O + qkbase;
  unsigned short* sPw = sP[wid];

  const int kKeySub = lane >> 4;               // K: 4 key rows per issue
  const int kPhys   = lane & 15;               // 16 chunks per 256B K row
  const int vFeatSub = lane >> 3;              // VT: 8 feat rows per issue
  const int vPhys    = lane & 7;               // 8 chunks per 128B VT row

  bf16x8 qf[8];
  #pragma unroll
  for (int ks = 0; ks < 8; ++ks)
    qf[ks] = *(const bf16x8*)(Qg + (size_t)(qw + l32) * D_ + ks * 16 + half * 8);

  union { unsigned short u[8]; bf16x8 v; } onesu;
  #pragma unroll
  for (int j2 = 0; j2 < 8; ++j2) onesu.u[j2] = 0x3F80;  // bf16 1.0
  const bf16x8 ones = onesu.v;

  f32x16 Oacc[4];
  #pragma unroll
  for (int ft = 0; ft < 4; ++ft)
    #pragma unroll
    for (int r = 0; r < 16; ++r) Oacc[ft][r] = 0.f;
  f32x16 l_acc;
  #pragma unroll
  for (int r = 0; r < 16; ++r) l_acc[r] = 0.f;
  const float scale = 0.08838834764831845f;    // 1/sqrt(128)

  const int nkb = 2 * (qi + 1);

  auto stage = [&](int kb) {
    const int k0 = kb * 64;
    unsigned short* bK = sK[kb & 1];
    unsigned short* bV = sVT[kb & 1];
    #pragma unroll
    for (int p = 0; p < 4; ++p) {
      int issue = wid * 4 + p;                 // 0..15
      int key = issue * 4 + kKeySub;
      int logiK = (kPhys & 8) | ((kPhys ^ key) & 7);
      gld16(Kg + (size_t)(k0 + key) * D_ + logiK * 8, bK + issue * 512);
      int feat = issue * 8 + vFeatSub;
      int logiV = vPhys ^ (feat & 7);
      gld16(VTg + (size_t)feat * S_ + k0 + logiV * 8, bV + issue * 512);
    }
  };

  stage(0);

  for (int kb = 0; kb < nkb; ++kb) {
    __syncthreads();   // drains vmcnt: buf[kb&1] ready; prior reads of other buf done
    if (kb + 1 < nkb) stage(kb + 1);

    const int k0 = kb * 64;
    if (k0 > qw + 31) continue;                // fully-masked for this wave (uniform)

    const unsigned short* bK = sK[kb & 1];
    const unsigned short* bV = sVT[kb & 1];

    f32x16 sc[2];
    #pragma unroll
    for (int t = 0; t < 2; ++t)
      #pragma unroll
      for (int r = 0; r < 16; ++r) sc[t][r] = 0.f;
    #pragma unroll
    for (int ks = 0; ks < 8; ++ks) {
      const int logi = ks * 2 + half;
      #pragma unroll
      for (int t = 0; t < 2; ++t) {
        const int key = t * 32 + l32;
        const int phys = (logi & 8) | ((logi ^ key) & 7);
        bf16x8 kf = *(const bf16x8*)(bK + key * 128 + phys * 8);
        sc[t] = __builtin_amdgcn_mfma_f32_32x32x16_bf16(qf[ks], kf, sc[t], 0, 0, 0);
      }
    }

    const bool diag = (k0 + 63 > qw);
    #pragma unroll
    for (int t = 0; t < 2; ++t) {
      const int col = t * 32 + l32;
      const int keyg = k0 + col;
      #pragma unroll
      for (int r = 0; r < 16; ++r) {
        const int rl = (r & 3) + 8 * (r >> 2) + 4 * half;
        float v = sc[t][r] * scale;
        if (diag && (keyg > qw + rl)) v = -1e30f;
        sPw[rl * 64 + (((col >> 3) ^ (rl & 7)) * 8) + (col & 7)] = f2bf(__expf(v));
      }
    }

    #pragma unroll
    for (int ksp = 0; ksp < 4; ++ksp) {
      const int logi = ksp * 2 + half;
      bf16x8 pf = *(const bf16x8*)(sPw + l32 * 64 + ((logi ^ (l32 & 7)) * 8));
      l_acc = __builtin_amdgcn_mfma_f32_32x32x16_bf16(pf, ones, l_acc, 0, 0, 0);
      #pragma unroll
      for (int ft = 0; ft < 4; ++ft) {
        const int feat = ft * 32 + l32;
        const int phys = logi ^ (feat & 7);
        bf16x8 vf = *(const bf16x8*)(bV + feat * 64 + phys * 8);
        Oacc[ft] = __builtin_amdgcn_mfma_f32_32x32x16_bf16(pf, vf, Oacc[ft], 0, 0, 0);
      }
    }
  }

  #pragma unroll
  for (int ft = 0; ft < 4; ++ft) {
    const int feat = ft * 32 + l32;
    #pragma unroll
    for (int r = 0; r < 16; ++r) {
      const int rl = (r & 3) + 8 * (r >> 2) + 4 * half;
      Og[(size_t)(qw + rl) * D_ + feat] = f2bf(Oacc[ft][r] / l_acc[r]);
    }
  }
}

// ---------------- launch ----------------
extern "C" void kernel_launch(void* const* d_in, const int* in_sizes, int n_in,
                              void* d_out, int out_size, void* d_ws, size_t ws_size,
                              hipStream_t stream) {
  const float* x  = (const float*)d_in[0];
  const float* Wq = (const float*)d_in[1];
  const float* Wk = (const float*)d_in[2];
  const float* Wv = (const float*)d_in[3];
  const float* Wo = (const float*)d_in[4];
  const int*  pos = (const int*)d_in[5];
  float* out = (float*)d_out;

  char* ws = (char*)d_ws;
  size_t off = 0;
  auto alloc = [&](size_t bytes) { void* p = ws + off; off += (bytes + 255) & ~255ULL; return p; };
  const size_t nx = (size_t)M_ * D_;
  const size_t nw = (size_t)D_ * D_;
  unsigned short* xb  = (unsigned short*)alloc(nx * 2);
  unsigned short* wqb = (unsigned short*)alloc(nw * 2);
  unsigned short* wkb = (unsigned short*)alloc(nw * 2);
  unsigned short* wvb = (unsigned short*)alloc(nw * 2);
  unsigned short* wob = (unsigned short*)alloc(nw * 2);
  unsigned short* Qb  = (unsigned short*)alloc(nx * 2);
  unsigned short* Kb  = (unsigned short*)alloc(nx * 2);
  unsigned short* Vb  = (unsigned short*)alloc(nx * 2);
  unsigned short* AOb = xb;   // alias: x_bf16 dead after QKV projection
  unsigned short* VTb = wqb;  // alias: Wq/Wk bf16 dead after QKV projection

  // single fused cvt: dst regions xb|wqb|wkb|wvb|wob are contiguous (each 256B-aligned size)
  hipLaunchKernelGGL(cvt_all, dim3((nx + 4 * nw) / 1024), dim3(256), 0, stream,
                     x, Wq, Wk, Wv, Wo, xb);

  // fused QKV projection: 256^2 8-phase, grid.z = 3
  hipLaunchKernelGGL((gemm8p<1>), dim3(D_ / 256, M_ / 256, 3), dim3(512), 0, stream,
                     xb, wqb, wkb, wvb, (void*)Qb, (void*)Kb, (void*)Vb, M_, D_, D_);

  hipLaunchKernelGGL(rope_kernel, dim3((B_ * S_ * H_ * 64) / 256), dim3(256), 0, stream, Qb, Kb, pos);

  // V -> VT (per-b 2048x2048 transpose), into dead Wq/Wk bf16 space
  hipLaunchKernelGGL(transpose_bf16, dim3(1024, 2), dim3(256), 0, stream, Vb, VTb);

  hipLaunchKernelGGL(flash_attn, dim3(B_ * H_ * (S_ / 128)), dim3(256), 0, stream, Qb, Kb, VTb, AOb);

  // out-projection: 128^2 m97-style (512 blocks = 2 exact full-machine rounds)
  hipLaunchKernelGGL((gemm_bt<0>), dim3(D_ / 128, M_ / 128, 1), dim3(256), 0, stream,
                     AOb, wob, wob, wob, (void*)out, (void*)out, (void*)out, M_, D_, D_);
}

// Round 5
// 415.457 us; speedup vs baseline: 1.1063x; 1.0555x over previous
//
#include <hip/hip_runtime.h>
#include <hip/hip_bf16.h>
#include <cstdint>
#include <cstddef>

#define B_ 2
#define S_ 2048
#define D_ 2048
#define H_ 16
#define DK_ 128
#define M_ (B_*S_)   // 4096

typedef __attribute__((ext_vector_type(8))) __bf16 bf16x8;
typedef __attribute__((ext_vector_type(4))) float f32x4;
typedef __attribute__((ext_vector_type(16))) float f32x16;

__device__ __forceinline__ unsigned short f2bf(float f) {
  union { float f; unsigned int u; } v; v.f = f;
  unsigned int r = (v.u + 0x7fffu + ((v.u >> 16) & 1u)) >> 16;
  return (unsigned short)r;
}
__device__ __forceinline__ float bf2f(unsigned short b) {
  union { unsigned int u; float f; } v; v.u = ((unsigned int)b) << 16;
  return v.f;
}

// async global->LDS, 16B per lane; LDS dest is wave-uniform base + lane*16
__device__ __forceinline__ void gld16(const void* g, void* l) {
  __builtin_amdgcn_global_load_lds(
      (const __attribute__((address_space(1))) unsigned int*)g,
      (__attribute__((address_space(3))) unsigned int*)l, 16, 0, 0);
}

// ---------------- fused fp32 -> bf16 for x|Wq|Wk|Wv|Wo (contiguous dst) ----------------
__global__ void cvt_all(const float* __restrict__ x,  const float* __restrict__ Wq,
                        const float* __restrict__ Wk, const float* __restrict__ Wv,
                        const float* __restrict__ Wo, unsigned short* __restrict__ dst) {
  size_t i = ((size_t)blockIdx.x * blockDim.x + threadIdx.x) * 4;
  const float* src;
  size_t off;
  if (i < ((size_t)M_ * D_)) {            // x region (2^23)
    src = x; off = i;
  } else {
    size_t j = i - (size_t)M_ * D_;
    int w = (int)(j >> 22);               // nw = 2^22
    off = j & ((1u << 22) - 1);
    src = (w == 0) ? Wq : (w == 1) ? Wk : (w == 2) ? Wv : Wo;
  }
  float4 v = *(const float4*)(src + off);
  dst[i+0] = f2bf(v.x); dst[i+1] = f2bf(v.y);
  dst[i+2] = f2bf(v.z); dst[i+3] = f2bf(v.w);
}

// ---------------- QKV projection, single 512-block dispatch ----------------
// Blocks 0..255: Q (z=0) / K (z=1) at 256x256 tiles, 8-phase schedule (round-4 verified body).
// Blocks 256..511: V at 128x256 tiles, same skeleton, 2 fat phases/K-tile, vmcnt(3).
// 512 equal-LDS blocks -> greedy backfill packs 1.5 heavy-equivalents per CU, no idle round.
__global__ __launch_bounds__(512, 2) void gemm_qkv(const unsigned short* __restrict__ A,
                                                   const unsigned short* __restrict__ W0,
                                                   const unsigned short* __restrict__ W1,
                                                   const unsigned short* __restrict__ W2,
                                                   unsigned short* __restrict__ C0,
                                                   unsigned short* __restrict__ C1,
                                                   unsigned short* __restrict__ C2,
                                                   int M, int N, int K) {
  __shared__ unsigned short sA[2][2][256 * 32];   // [buf][khalf][rows x 32 k]
  __shared__ unsigned short sB[2][2][256 * 32];
  const int id   = blockIdx.x;
  const int tid  = threadIdx.x;
  const int lane = tid & 63;
  const int wid  = tid >> 6;
  const int l16 = lane & 15, quad = lane >> 4;
  const int col16 = quad ^ ((lane >> 1) & 3);        // swizzled 16B chunk for frag reads
  const int qk_log = (lane & 3) ^ ((lane >> 3) & 3); // inverse swizzle for staging source
  const int srow = lane >> 2;                        // staging row within 16-row group
  const int NT = K >> 6;                             // K-tiles of 64

  if (id < 256) {
    // ---------------- heavy path: 256x256, Q/K (verified round-4 body) ----------------
    const int z = id >> 7, r = id & 127;
    const unsigned short* Bt = z ? W1 : W0;
    unsigned short* Cout = z ? C1 : C0;
    const int bm = (r >> 3) * 256, bn = (r & 7) * 256;
    const int wm = wid >> 2, wn = wid & 3;           // wave tile: rows wm*128, cols wn*64

    f32x4 acc[8][4];
    #pragma unroll
    for (int i = 0; i < 8; ++i)
      #pragma unroll
      for (int j = 0; j < 4; ++j)
        acc[i][j] = (f32x4){0.f, 0.f, 0.f, 0.f};

    auto stage = [&](const unsigned short* __restrict__ g, int rowbase,
                     unsigned short* l, int t, int kh) {
      const unsigned short* src = g + (size_t)rowbase * K + t * 64 + kh * 32 + qk_log * 8;
      #pragma unroll
      for (int p = 0; p < 2; ++p) {
        const int i = wid * 2 + p;                   // issue 0..15, 16 rows each
        gld16(src + (size_t)(i * 16 + srow) * K, l + i * 512);
      }
    };

    stage(A,  bm, &sA[0][0][0], 0, 0);
    stage(Bt, bn, &sB[0][0][0], 0, 0);
    stage(A,  bm, &sA[0][1][0], 0, 1);
    stage(Bt, bn, &sB[0][1][0], 0, 1);
    stage(A,  bm, &sA[1][0][0], 1, 0);
    stage(Bt, bn, &sB[1][0][0], 1, 0);
    asm volatile("s_waitcnt vmcnt(4)" ::: "memory");
    __builtin_amdgcn_s_barrier();

    for (int t = 0; t < NT; ++t) {
      const int buf = t & 1;
      bf16x8 bfrag[4];
      #pragma unroll
      for (int ph = 0; ph < 4; ++ph) {
        const int ks = ph >> 1;
        const int mh = ph & 1;
        bf16x8 afrag[4];
        const unsigned short* aP = &sA[buf][ks][0] +
            (size_t)((wm * 128 + mh * 64 + l16) * 4 + col16) * 8;
        #pragma unroll
        for (int mf = 0; mf < 4; ++mf)
          afrag[mf] = *(const bf16x8*)(aP + mf * 512);
        if (mh == 0) {
          const unsigned short* bP = &sB[buf][ks][0] +
              (size_t)((wn * 64 + l16) * 4 + col16) * 8;
          #pragma unroll
          for (int nf = 0; nf < 4; ++nf)
            bfrag[nf] = *(const bf16x8*)(bP + nf * 512);
        }
        if (ph == 0)      { if (t + 1 < NT) stage(A,  bm, &sA[buf ^ 1][1][0], t + 1, 1); }
        else if (ph == 1) { if (t + 1 < NT) stage(Bt, bn, &sB[buf ^ 1][1][0], t + 1, 1); }
        else if (ph == 2) { if (t + 2 < NT) stage(A,  bm, &sA[buf][0][0],     t + 2, 0); }
        else              { if (t + 2 < NT) stage(Bt, bn, &sB[buf][0][0],     t + 2, 0); }

        __builtin_amdgcn_s_barrier();
        asm volatile("s_waitcnt lgkmcnt(0)" ::: "memory");
        __builtin_amdgcn_s_setprio(1);
        #pragma unroll
        for (int nf = 0; nf < 4; ++nf)
          #pragma unroll
          for (int mf = 0; mf < 4; ++mf)
            acc[mh * 4 + mf][nf] = __builtin_amdgcn_mfma_f32_16x16x32_bf16(
                afrag[mf], bfrag[nf], acc[mh * 4 + mf][nf], 0, 0, 0);
        __builtin_amdgcn_s_setprio(0);
        if (ph == 3) {
          if (t + 2 < NT) asm volatile("s_waitcnt vmcnt(4)" ::: "memory");
          else            asm volatile("s_waitcnt vmcnt(0)" ::: "memory");
        }
        __builtin_amdgcn_s_barrier();
      }
    }

    #pragma unroll
    for (int mf = 0; mf < 8; ++mf) {
      const int row = bm + wm * 128 + mf * 16 + quad * 4;
      #pragma unroll
      for (int nf = 0; nf < 4; ++nf) {
        const int col = bn + wn * 64 + nf * 16 + l16;
        #pragma unroll
        for (int rr = 0; rr < 4; ++rr)
          Cout[(size_t)(row + rr) * N + col] = f2bf(acc[mf][nf][rr]);
      }
    }
  } else {
    // ---------------- light path: 128x256, V; 2 fat phases/K-tile ----------------
    const int r = id - 256;
    const unsigned short* Bt = W2;
    unsigned short* Cout = C2;
    const int bm = (r >> 3) * 128, bn = (r & 7) * 256;
    const int wm = wid >> 2, wn = wid & 3;           // wave tile: rows wm*64, cols wn*64

    f32x4 acc[4][4];
    #pragma unroll
    for (int i = 0; i < 4; ++i)
      #pragma unroll
      for (int j = 0; j < 4; ++j)
        acc[i][j] = (f32x4){0.f, 0.f, 0.f, 0.f};

    auto stageB = [&](unsigned short* l, int t, int kh) {   // 256 rows, 2 issues/wave
      const unsigned short* src = Bt + (size_t)bn * K + t * 64 + kh * 32 + qk_log * 8;
      #pragma unroll
      for (int p = 0; p < 2; ++p) {
        const int i = wid * 2 + p;
        gld16(src + (size_t)(i * 16 + srow) * K, l + i * 512);
      }
    };
    auto stageA = [&](unsigned short* l, int t, int kh) {   // 128 rows, 1 issue/wave
      const unsigned short* src = A + (size_t)bm * K + t * 64 + kh * 32 + qk_log * 8;
      gld16(src + (size_t)(wid * 16 + srow) * K, l + wid * 512);
    };

    // prologue: t0 kh0(A1+B2), t0 kh1(3), t1 kh0(3) = 9 loads; leave t1 kh0 (3) in flight
    stageA(&sA[0][0][0], 0, 0); stageB(&sB[0][0][0], 0, 0);
    stageA(&sA[0][1][0], 0, 1); stageB(&sB[0][1][0], 0, 1);
    stageA(&sA[1][0][0], 1, 0); stageB(&sB[1][0][0], 1, 0);
    asm volatile("s_waitcnt vmcnt(3)" ::: "memory");
    __builtin_amdgcn_s_barrier();

    for (int t = 0; t < NT; ++t) {
      const int buf = t & 1;
      #pragma unroll
      for (int ph = 0; ph < 2; ++ph) {               // ph = K-half consumed
        bf16x8 afrag[4], bfrag[4];
        const unsigned short* aP = &sA[buf][ph][0] +
            (size_t)((wm * 64 + l16) * 4 + col16) * 8;
        #pragma unroll
        for (int mf = 0; mf < 4; ++mf)
          afrag[mf] = *(const bf16x8*)(aP + mf * 512);
        const unsigned short* bP = &sB[buf][ph][0] +
            (size_t)((wn * 64 + l16) * 4 + col16) * 8;
        #pragma unroll
        for (int nf = 0; nf < 4; ++nf)
          bfrag[nf] = *(const bf16x8*)(bP + nf * 512);

        if (ph == 0) { if (t + 1 < NT) { stageA(&sA[buf ^ 1][1][0], t + 1, 1);
                                         stageB(&sB[buf ^ 1][1][0], t + 1, 1); } }
        else         { if (t + 2 < NT) { stageA(&sA[buf][0][0], t + 2, 0);
                                         stageB(&sB[buf][0][0], t + 2, 0); } }

        __builtin_amdgcn_s_barrier();
        asm volatile("s_waitcnt lgkmcnt(0)" ::: "memory");
        __builtin_amdgcn_s_setprio(1);
        #pragma unroll
        for (int nf = 0; nf < 4; ++nf)
          #pragma unroll
          for (int mf = 0; mf < 4; ++mf)
            acc[mf][nf] = __builtin_amdgcn_mfma_f32_16x16x32_bf16(
                afrag[mf], bfrag[nf], acc[mf][nf], 0, 0, 0);
        __builtin_amdgcn_s_setprio(0);
        if (ph == 1) {
          if (t + 2 < NT) asm volatile("s_waitcnt vmcnt(3)" ::: "memory");
          else            asm volatile("s_waitcnt vmcnt(0)" ::: "memory");
        }
        __builtin_amdgcn_s_barrier();
      }
    }

    #pragma unroll
    for (int mf = 0; mf < 4; ++mf) {
      const int row = bm + wm * 64 + mf * 16 + quad * 4;
      #pragma unroll
      for (int nf = 0; nf < 4; ++nf) {
        const int col = bn + wn * 64 + nf * 16 + l16;
        #pragma unroll
        for (int rr = 0; rr < 4; ++rr)
          Cout[(size_t)(row + rr) * N + col] = f2bf(acc[mf][nf][rr]);
      }
    }
  }
}

// ---------------- 128x128 m97-style GEMM (out-proj: 512 blocks = 2 full rounds) ----------------
template<int WRITE_BF16>
__global__ __launch_bounds__(256) void gemm_bt(const unsigned short* __restrict__ A,
                                               const unsigned short* __restrict__ W0,
                                               const unsigned short* __restrict__ W1,
                                               const unsigned short* __restrict__ W2,
                                               void* __restrict__ C0, void* __restrict__ C1,
                                               void* __restrict__ C2,
                                               int M, int N, int K) {
  __shared__ unsigned short sA[128 * 32];
  __shared__ unsigned short sB[128 * 32];
  const int z = blockIdx.z;
  const unsigned short* Bt = (z == 0) ? W0 : (z == 1) ? W1 : W2;
  void* Cout = (z == 0) ? C0 : (z == 1) ? C1 : C2;

  const int tid  = threadIdx.x;
  const int lane = tid & 63;
  const int wid  = tid >> 6;
  const int wm = wid >> 1, wn = wid & 1;
  const int quad = lane >> 4, l16 = lane & 15;
  const int bm = blockIdx.y * 128, bn = blockIdx.x * 128;
  const int srow = lane >> 2;          // 0..15
  const int scol = (lane & 3) * 8;     // 0,8,16,24

  f32x4 acc[4][4];
  #pragma unroll
  for (int i = 0; i < 4; ++i)
    #pragma unroll
    for (int j = 0; j < 4; ++j)
      acc[i][j] = (f32x4){0.f, 0.f, 0.f, 0.f};

  for (int k0 = 0; k0 < K; k0 += 32) {
    __syncthreads();
    #pragma unroll
    for (int p = 0; p < 2; ++p) {
      int row = p * 64 + wid * 16;
      gld16(A  + (size_t)(bm + row + srow) * K + k0 + scol, sA + row * 32);
      gld16(Bt + (size_t)(bn + row + srow) * K + k0 + scol, sB + row * 32);
    }
    __syncthreads();

    bf16x8 af[4], bfr[4];
    #pragma unroll
    for (int i = 0; i < 4; ++i)
      af[i] = *(const bf16x8*)(sA + (wm * 64 + i * 16 + l16) * 32 + quad * 8);
    #pragma unroll
    for (int j = 0; j < 4; ++j)
      bfr[j] = *(const bf16x8*)(sB + (wn * 64 + j * 16 + l16) * 32 + quad * 8);
    #pragma unroll
    for (int i = 0; i < 4; ++i)
      #pragma unroll
      for (int j = 0; j < 4; ++j)
        acc[i][j] = __builtin_amdgcn_mfma_f32_16x16x32_bf16(af[i], bfr[j], acc[i][j], 0, 0, 0);
  }

  #pragma unroll
  for (int i = 0; i < 4; ++i) {
    int row = bm + wm * 64 + i * 16 + quad * 4;
    #pragma unroll
    for (int j = 0; j < 4; ++j) {
      int col = bn + wn * 64 + j * 16 + l16;
      #pragma unroll
      for (int r = 0; r < 4; ++r) {
        if (WRITE_BF16)
          ((unsigned short*)Cout)[(size_t)(row + r) * N + col] = f2bf(acc[i][j][r]);
        else
          ((float*)Cout)[(size_t)(row + r) * N + col] = acc[i][j][r];
      }
    }
  }
}

// ---------------- RoPE (in-place on bf16 Q and K), fast intrinsics + packed 4B I/O ----------------
__global__ void rope_kernel(unsigned short* __restrict__ Q, unsigned short* __restrict__ K,
                            const int* __restrict__ pos) {
  int idx = blockIdx.x * blockDim.x + threadIdx.x;
  int i = idx & 63;
  int h = (idx >> 6) & (H_ - 1);
  int s = (idx >> 10) & (S_ - 1);
  int b = idx >> 21;
  float p = (float)pos[s];
  float inv = __expf(-(float)i * (9.210340371976184f / 64.0f));
  float ang = p * inv;
  float sn, cs;
  __sincosf(ang, &sn, &cs);
  size_t base = (((size_t)b * S_ + s) * D_) + (size_t)h * DK_ + 2 * i;
  unsigned int q2 = *(const unsigned int*)(Q + base);
  float x1 = bf2f((unsigned short)(q2 & 0xffffu)), x2 = bf2f((unsigned short)(q2 >> 16));
  unsigned int lo = f2bf(x1 * cs - x2 * sn), hi = f2bf(x1 * sn + x2 * cs);
  *(unsigned int*)(Q + base) = lo | (hi << 16);
  unsigned int k2 = *(const unsigned int*)(K + base);
  x1 = bf2f((unsigned short)(k2 & 0xffffu)); x2 = bf2f((unsigned short)(k2 >> 16));
  lo = f2bf(x1 * cs - x2 * sn); hi = f2bf(x1 * sn + x2 * cs);
  *(unsigned int*)(K + base) = lo | (hi << 16);
}

// ---------------- V transpose: per b, VT[col][m] = V[m][col] ----------------
__global__ __launch_bounds__(256) void transpose_bf16(const unsigned short* __restrict__ src,
                                                      unsigned short* __restrict__ dst) {
  __shared__ unsigned short sT[64 * 64];
  const int b = blockIdx.y;
  const int tx = blockIdx.x & 31, ty = blockIdx.x >> 5;
  const size_t base = (size_t)b * 2048 * 2048;
  const int m0 = ty * 64, c0 = tx * 64;
  const int tid = threadIdx.x;
  #pragma unroll
  for (int c = 0; c < 2; ++c) {
    int idx = tid + c * 256;
    int row = idx >> 3;               // 0..63 (m)
    int chk = idx & 7;                // col chunk
    uint4 v = *(const uint4*)(src + base + (size_t)(m0 + row) * 2048 + c0 + chk * 8);
    *(uint4*)(sT + row * 64 + ((chk ^ (row & 7)) * 8)) = v;
  }
  __syncthreads();
  #pragma unroll
  for (int c = 0; c < 2; ++c) {
    int idx = tid + c * 256;
    int orow = idx >> 3;              // output row = col index
    int ocol = (idx & 7) * 8;         // output col = m index
    unsigned short tmp[8];
    #pragma unroll
    for (int j = 0; j < 8; ++j) {
      int lr = ocol + j;              // logical row (m)
      int lc = orow;                  // logical col
      tmp[j] = sT[lr * 64 + (((lc >> 3) ^ (lr & 7)) * 8) + (lc & 7)];
    }
    *(uint4*)(dst + base + (size_t)(c0 + orow) * 2048 + m0 + ocol) = *(const uint4*)tmp;
  }
}

// ---------------- Flash attention (causal), 32x32 MFMA, pipelined staging ----------------
// Heavy-first ordering (qi = 15-j) + greedy refill; T5 setprio around MFMA clusters.
__global__ __launch_bounds__(256, 2) void flash_attn(const unsigned short* __restrict__ Q,
                                                     const unsigned short* __restrict__ K,
                                                     const unsigned short* __restrict__ VT,
                                                     unsigned short* __restrict__ O) {
  __shared__ unsigned short sK[2][64 * 128];   // [buf][key][feat-chunk swz] 16KB each
  __shared__ unsigned short sVT[2][128 * 64];  // [buf][feat][key-chunk swz] 16KB each
  __shared__ unsigned short sP[4][32 * 64];    // per-wave 32x64 P, swz, 4KB each

  const int tid = threadIdx.x, lane = tid & 63, wid = tid >> 6;
  const int half = lane >> 5, l32 = lane & 31;
  const int qi = 15 - (blockIdx.x & 15);       // 16 q-blocks of 128 rows; heavy first
  const int bh = blockIdx.x >> 4;
  const int h = bh & (H_ - 1), b = bh >> 4;
  const int qw = qi * 128 + wid * 32;          // this wave's first Q row
  const size_t qkbase = ((size_t)b * S_) * D_ + (size_t)h * DK_;
  const unsigned short* Qg = Q + qkbase;
  const unsigned short* Kg = K + qkbase;
  const unsigned short* VTg = VT + (size_t)bh * DK_ * S_;   // [dk][s]
  unsigned short* Og = O + qkbase;
  unsigned short* sPw = sP[wid];

  const int kKeySub = lane >> 4;               // K: 4 key rows per issue
  const int kPhys   = lane & 15;               // 16 chunks per 256B K row
  const int vFeatSub = lane >> 3;              // VT: 8 feat rows per issue
  const int vPhys    = lane & 7;               // 8 chunks per 128B VT row

  bf16x8 qf[8];
  #pragma unroll
  for (int ks = 0; ks < 8; ++ks)
    qf[ks] = *(const bf16x8*)(Qg + (size_t)(qw + l32) * D_ + ks * 16 + half * 8);

  union { unsigned short u[8]; bf16x8 v; } onesu;
  #pragma unroll
  for (int j2 = 0; j2 < 8; ++j2) onesu.u[j2] = 0x3F80;  // bf16 1.0
  const bf16x8 ones = onesu.v;

  f32x16 Oacc[4];
  #pragma unroll
  for (int ft = 0; ft < 4; ++ft)
    #pragma unroll
    for (int r = 0; r < 16; ++r) Oacc[ft][r] = 0.f;
  f32x16 l_acc;
  #pragma unroll
  for (int r = 0; r < 16; ++r) l_acc[r] = 0.f;
  const float scale = 0.08838834764831845f;    // 1/sqrt(128)

  const int nkb = 2 * (qi + 1);

  auto stage = [&](int kb) {
    const int k0 = kb * 64;
    unsigned short* bK = sK[kb & 1];
    unsigned short* bV = sVT[kb & 1];
    #pragma unroll
    for (int p = 0; p < 4; ++p) {
      int issue = wid * 4 + p;                 // 0..15
      int key = issue * 4 + kKeySub;
      int logiK = (kPhys & 8) | ((kPhys ^ key) & 7);
      gld16(Kg + (size_t)(k0 + key) * D_ + logiK * 8, bK + issue * 512);
      int feat = issue * 8 + vFeatSub;
      int logiV = vPhys ^ (feat & 7);
      gld16(VTg + (size_t)feat * S_ + k0 + logiV * 8, bV + issue * 512);
    }
  };

  stage(0);

  for (int kb = 0; kb < nkb; ++kb) {
    __syncthreads();   // drains vmcnt: buf[kb&1] ready; prior reads of other buf done
    if (kb + 1 < nkb) stage(kb + 1);

    const int k0 = kb * 64;
    if (k0 > qw + 31) continue;                // fully-masked for this wave (uniform)

    const unsigned short* bK = sK[kb & 1];
    const unsigned short* bV = sVT[kb & 1];

    f32x16 sc[2];
    #pragma unroll
    for (int t = 0; t < 2; ++t)
      #pragma unroll
      for (int r = 0; r < 16; ++r) sc[t][r] = 0.f;
    __builtin_amdgcn_s_setprio(1);
    #pragma unroll
    for (int ks = 0; ks < 8; ++ks) {
      const int logi = ks * 2 + half;
      #pragma unroll
      for (int t = 0; t < 2; ++t) {
        const int key = t * 32 + l32;
        const int phys = (logi & 8) | ((logi ^ key) & 7);
        bf16x8 kf = *(const bf16x8*)(bK + key * 128 + phys * 8);
        sc[t] = __builtin_amdgcn_mfma_f32_32x32x16_bf16(qf[ks], kf, sc[t], 0, 0, 0);
      }
    }
    __builtin_amdgcn_s_setprio(0);

    const bool diag = (k0 + 63 > qw);
    #pragma unroll
    for (int t = 0; t < 2; ++t) {
      const int col = t * 32 + l32;
      const int keyg = k0 + col;
      #pragma unroll
      for (int r = 0; r < 16; ++r) {
        const int rl = (r & 3) + 8 * (r >> 2) + 4 * half;
        float v = sc[t][r] * scale;
        if (diag && (keyg > qw + rl)) v = -1e30f;
        sPw[rl * 64 + (((col >> 3) ^ (rl & 7)) * 8) + (col & 7)] = f2bf(__expf(v));
      }
    }

    __builtin_amdgcn_s_setprio(1);
    #pragma unroll
    for (int ksp = 0; ksp < 4; ++ksp) {
      const int logi = ksp * 2 + half;
      bf16x8 pf = *(const bf16x8*)(sPw + l32 * 64 + ((logi ^ (l32 & 7)) * 8));
      l_acc = __builtin_amdgcn_mfma_f32_32x32x16_bf16(pf, ones, l_acc, 0, 0, 0);
      #pragma unroll
      for (int ft = 0; ft < 4; ++ft) {
        const int feat = ft * 32 + l32;
        const int phys = logi ^ (feat & 7);
        bf16x8 vf = *(const bf16x8*)(bV + feat * 64 + phys * 8);
        Oacc[ft] = __builtin_amdgcn_mfma_f32_32x32x16_bf16(pf, vf, Oacc[ft], 0, 0, 0);
      }
    }
    __builtin_amdgcn_s_setprio(0);
  }

  #pragma unroll
  for (int ft = 0; ft < 4; ++ft) {
    const int feat = ft * 32 + l32;
    #pragma unroll
    for (int r = 0; r < 16; ++r) {
      const int rl = (r & 3) + 8 * (r >> 2) + 4 * half;
      Og[(size_t)(qw + rl) * D_ + feat] = f2bf(Oacc[ft][r] / l_acc[r]);
    }
  }
}

// ---------------- launch ----------------
extern "C" void kernel_launch(void* const* d_in, const int* in_sizes, int n_in,
                              void* d_out, int out_size, void* d_ws, size_t ws_size,
                              hipStream_t stream) {
  const float* x  = (const float*)d_in[0];
  const float* Wq = (const float*)d_in[1];
  const float* Wk = (const float*)d_in[2];
  const float* Wv = (const float*)d_in[3];
  const float* Wo = (const float*)d_in[4];
  const int*  pos = (const int*)d_in[5];
  float* out = (float*)d_out;

  char* ws = (char*)d_ws;
  size_t off = 0;
  auto alloc = [&](size_t bytes) { void* p = ws + off; off += (bytes + 255) & ~255ULL; return p; };
  const size_t nx = (size_t)M_ * D_;
  const size_t nw = (size_t)D_ * D_;
  unsigned short* xb  = (unsigned short*)alloc(nx * 2);
  unsigned short* wqb = (unsigned short*)alloc(nw * 2);
  unsigned short* wkb = (unsigned short*)alloc(nw * 2);
  unsigned short* wvb = (unsigned short*)alloc(nw * 2);
  unsigned short* wob = (unsigned short*)alloc(nw * 2);
  unsigned short* Qb  = (unsigned short*)alloc(nx * 2);
  unsigned short* Kb  = (unsigned short*)alloc(nx * 2);
  unsigned short* Vb  = (unsigned short*)alloc(nx * 2);
  unsigned short* AOb = xb;   // alias: x_bf16 dead after QKV projection
  unsigned short* VTb = wqb;  // alias: Wq/Wk bf16 dead after QKV projection

  // single fused cvt: dst regions xb|wqb|wkb|wvb|wob are contiguous
  hipLaunchKernelGGL(cvt_all, dim3((nx + 4 * nw) / 1024), dim3(256), 0, stream,
                     x, Wq, Wk, Wv, Wo, xb);

  // fused QKV projection: one 512-block dispatch (256 heavy QK + 256 light V tiles)
  hipLaunchKernelGGL(gemm_qkv, dim3(512), dim3(512), 0, stream,
                     xb, wqb, wkb, wvb, Qb, Kb, Vb, M_, D_, D_);

  hipLaunchKernelGGL(rope_kernel, dim3((B_ * S_ * H_ * 64) / 256), dim3(256), 0, stream, Qb, Kb, pos);

  // V -> VT (per-b 2048x2048 transpose), into dead Wq/Wk bf16 space
  hipLaunchKernelGGL(transpose_bf16, dim3(1024, 2), dim3(256), 0, stream, Vb, VTb);

  hipLaunchKernelGGL(flash_attn, dim3(B_ * H_ * (S_ / 128)), dim3(256), 0, stream, Qb, Kb, VTb, AOb);

  // out-projection: 128^2 m97-style (512 blocks = 2 exact full-machine rounds)
  hipLaunchKernelGGL((gemm_bt<0>), dim3(D_ / 128, M_ / 128, 1), dim3(256), 0, stream,
                     AOb, wob, wob, wob, (void*)out, (void*)out, (void*)out, M_, D_, D_);
}

// Round 6
// 411.354 us; speedup vs baseline: 1.1173x; 1.0100x over previous
//
#include <hip/hip_runtime.h>
#include <hip/hip_bf16.h>
#include <cstdint>
#include <cstddef>

#define B_ 2
#define S_ 2048
#define D_ 2048
#define H_ 16
#define DK_ 128
#define M_ (B_*S_)   // 4096

typedef __attribute__((ext_vector_type(8))) __bf16 bf16x8;
typedef __attribute__((ext_vector_type(4))) float f32x4;
typedef __attribute__((ext_vector_type(16))) float f32x16;

__device__ __forceinline__ unsigned short f2bf(float f) {
  union { float f; unsigned int u; } v; v.f = f;
  unsigned int r = (v.u + 0x7fffu + ((v.u >> 16) & 1u)) >> 16;
  return (unsigned short)r;
}
__device__ __forceinline__ float bf2f(unsigned short b) {
  union { unsigned int u; float f; } v; v.u = ((unsigned int)b) << 16;
  return v.f;
}

// async global->LDS, 16B per lane; LDS dest is wave-uniform base + lane*16
__device__ __forceinline__ void gld16(const void* g, void* l) {
  __builtin_amdgcn_global_load_lds(
      (const __attribute__((address_space(1))) unsigned int*)g,
      (__attribute__((address_space(3))) unsigned int*)l, 16, 0, 0);
}

// ---------------- fused fp32 -> bf16 for x|Wq|Wk|Wv|Wo (contiguous dst) ----------------
__global__ void cvt_all(const float* __restrict__ x,  const float* __restrict__ Wq,
                        const float* __restrict__ Wk, const float* __restrict__ Wv,
                        const float* __restrict__ Wo, unsigned short* __restrict__ dst) {
  size_t i = ((size_t)blockIdx.x * blockDim.x + threadIdx.x) * 4;
  const float* src;
  size_t off;
  if (i < ((size_t)M_ * D_)) {            // x region (2^23)
    src = x; off = i;
  } else {
    size_t j = i - (size_t)M_ * D_;
    int w = (int)(j >> 22);               // nw = 2^22
    off = j & ((1u << 22) - 1);
    src = (w == 0) ? Wq : (w == 1) ? Wk : (w == 2) ? Wv : Wo;
  }
  float4 v = *(const float4*)(src + off);
  dst[i+0] = f2bf(v.x); dst[i+1] = f2bf(v.y);
  dst[i+2] = f2bf(v.z); dst[i+3] = f2bf(v.w);
}

// ---------------- QKV projection, single 512-block dispatch ----------------
// Blocks 0..255: Q (z=0) / K (z=1) at 256x256 tiles, 8-phase schedule.
// Blocks 256..511: V at 128x256 tiles, same skeleton, 2 fat phases/K-tile, vmcnt(3).
__global__ __launch_bounds__(512, 2) void gemm_qkv(const unsigned short* __restrict__ A,
                                                   const unsigned short* __restrict__ W0,
                                                   const unsigned short* __restrict__ W1,
                                                   const unsigned short* __restrict__ W2,
                                                   unsigned short* __restrict__ C0,
                                                   unsigned short* __restrict__ C1,
                                                   unsigned short* __restrict__ C2,
                                                   int M, int N, int K) {
  __shared__ unsigned short sA[2][2][256 * 32];   // [buf][khalf][rows x 32 k]
  __shared__ unsigned short sB[2][2][256 * 32];
  const int id   = blockIdx.x;
  const int tid  = threadIdx.x;
  const int lane = tid & 63;
  const int wid  = tid >> 6;
  const int l16 = lane & 15, quad = lane >> 4;
  const int col16 = quad ^ ((lane >> 1) & 3);        // swizzled 16B chunk for frag reads
  const int qk_log = (lane & 3) ^ ((lane >> 3) & 3); // inverse swizzle for staging source
  const int srow = lane >> 2;                        // staging row within 16-row group
  const int NT = K >> 6;                             // K-tiles of 64

  if (id < 256) {
    // ---------------- heavy path: 256x256, Q/K ----------------
    const int z = id >> 7, r = id & 127;
    const unsigned short* Bt = z ? W1 : W0;
    unsigned short* Cout = z ? C1 : C0;
    const int bm = (r >> 3) * 256, bn = (r & 7) * 256;
    const int wm = wid >> 2, wn = wid & 3;           // wave tile: rows wm*128, cols wn*64

    f32x4 acc[8][4];
    #pragma unroll
    for (int i = 0; i < 8; ++i)
      #pragma unroll
      for (int j = 0; j < 4; ++j)
        acc[i][j] = (f32x4){0.f, 0.f, 0.f, 0.f};

    auto stage = [&](const unsigned short* __restrict__ g, int rowbase,
                     unsigned short* l, int t, int kh) {
      const unsigned short* src = g + (size_t)rowbase * K + t * 64 + kh * 32 + qk_log * 8;
      #pragma unroll
      for (int p = 0; p < 2; ++p) {
        const int i = wid * 2 + p;                   // issue 0..15, 16 rows each
        gld16(src + (size_t)(i * 16 + srow) * K, l + i * 512);
      }
    };

    stage(A,  bm, &sA[0][0][0], 0, 0);
    stage(Bt, bn, &sB[0][0][0], 0, 0);
    stage(A,  bm, &sA[0][1][0], 0, 1);
    stage(Bt, bn, &sB[0][1][0], 0, 1);
    stage(A,  bm, &sA[1][0][0], 1, 0);
    stage(Bt, bn, &sB[1][0][0], 1, 0);
    asm volatile("s_waitcnt vmcnt(4)" ::: "memory");
    __builtin_amdgcn_s_barrier();

    for (int t = 0; t < NT; ++t) {
      const int buf = t & 1;
      bf16x8 bfrag[4];
      #pragma unroll
      for (int ph = 0; ph < 4; ++ph) {
        const int ks = ph >> 1;
        const int mh = ph & 1;
        bf16x8 afrag[4];
        const unsigned short* aP = &sA[buf][ks][0] +
            (size_t)((wm * 128 + mh * 64 + l16) * 4 + col16) * 8;
        #pragma unroll
        for (int mf = 0; mf < 4; ++mf)
          afrag[mf] = *(const bf16x8*)(aP + mf * 512);
        if (mh == 0) {
          const unsigned short* bP = &sB[buf][ks][0] +
              (size_t)((wn * 64 + l16) * 4 + col16) * 8;
          #pragma unroll
          for (int nf = 0; nf < 4; ++nf)
            bfrag[nf] = *(const bf16x8*)(bP + nf * 512);
        }
        if (ph == 0)      { if (t + 1 < NT) stage(A,  bm, &sA[buf ^ 1][1][0], t + 1, 1); }
        else if (ph == 1) { if (t + 1 < NT) stage(Bt, bn, &sB[buf ^ 1][1][0], t + 1, 1); }
        else if (ph == 2) { if (t + 2 < NT) stage(A,  bm, &sA[buf][0][0],     t + 2, 0); }
        else              { if (t + 2 < NT) stage(Bt, bn, &sB[buf][0][0],     t + 2, 0); }

        __builtin_amdgcn_s_barrier();
        asm volatile("s_waitcnt lgkmcnt(0)" ::: "memory");
        __builtin_amdgcn_s_setprio(1);
        #pragma unroll
        for (int nf = 0; nf < 4; ++nf)
          #pragma unroll
          for (int mf = 0; mf < 4; ++mf)
            acc[mh * 4 + mf][nf] = __builtin_amdgcn_mfma_f32_16x16x32_bf16(
                afrag[mf], bfrag[nf], acc[mh * 4 + mf][nf], 0, 0, 0);
        __builtin_amdgcn_s_setprio(0);
        if (ph == 3) {
          if (t + 2 < NT) asm volatile("s_waitcnt vmcnt(4)" ::: "memory");
          else            asm volatile("s_waitcnt vmcnt(0)" ::: "memory");
        }
        __builtin_amdgcn_s_barrier();
      }
    }

    #pragma unroll
    for (int mf = 0; mf < 8; ++mf) {
      const int row = bm + wm * 128 + mf * 16 + quad * 4;
      #pragma unroll
      for (int nf = 0; nf < 4; ++nf) {
        const int col = bn + wn * 64 + nf * 16 + l16;
        #pragma unroll
        for (int rr = 0; rr < 4; ++rr)
          Cout[(size_t)(row + rr) * N + col] = f2bf(acc[mf][nf][rr]);
      }
    }
  } else {
    // ---------------- light path: 128x256, V; 2 fat phases/K-tile ----------------
    const int r = id - 256;
    const unsigned short* Bt = W2;
    unsigned short* Cout = C2;
    const int bm = (r >> 3) * 128, bn = (r & 7) * 256;
    const int wm = wid >> 2, wn = wid & 3;           // wave tile: rows wm*64, cols wn*64

    f32x4 acc[4][4];
    #pragma unroll
    for (int i = 0; i < 4; ++i)
      #pragma unroll
      for (int j = 0; j < 4; ++j)
        acc[i][j] = (f32x4){0.f, 0.f, 0.f, 0.f};

    auto stageB = [&](unsigned short* l, int t, int kh) {   // 256 rows, 2 issues/wave
      const unsigned short* src = Bt + (size_t)bn * K + t * 64 + kh * 32 + qk_log * 8;
      #pragma unroll
      for (int p = 0; p < 2; ++p) {
        const int i = wid * 2 + p;
        gld16(src + (size_t)(i * 16 + srow) * K, l + i * 512);
      }
    };
    auto stageA = [&](unsigned short* l, int t, int kh) {   // 128 rows, 1 issue/wave
      const unsigned short* src = A + (size_t)bm * K + t * 64 + kh * 32 + qk_log * 8;
      gld16(src + (size_t)(wid * 16 + srow) * K, l + wid * 512);
    };

    stageA(&sA[0][0][0], 0, 0); stageB(&sB[0][0][0], 0, 0);
    stageA(&sA[0][1][0], 0, 1); stageB(&sB[0][1][0], 0, 1);
    stageA(&sA[1][0][0], 1, 0); stageB(&sB[1][0][0], 1, 0);
    asm volatile("s_waitcnt vmcnt(3)" ::: "memory");
    __builtin_amdgcn_s_barrier();

    for (int t = 0; t < NT; ++t) {
      const int buf = t & 1;
      #pragma unroll
      for (int ph = 0; ph < 2; ++ph) {               // ph = K-half consumed
        bf16x8 afrag[4], bfrag[4];
        const unsigned short* aP = &sA[buf][ph][0] +
            (size_t)((wm * 64 + l16) * 4 + col16) * 8;
        #pragma unroll
        for (int mf = 0; mf < 4; ++mf)
          afrag[mf] = *(const bf16x8*)(aP + mf * 512);
        const unsigned short* bP = &sB[buf][ph][0] +
            (size_t)((wn * 64 + l16) * 4 + col16) * 8;
        #pragma unroll
        for (int nf = 0; nf < 4; ++nf)
          bfrag[nf] = *(const bf16x8*)(bP + nf * 512);

        if (ph == 0) { if (t + 1 < NT) { stageA(&sA[buf ^ 1][1][0], t + 1, 1);
                                         stageB(&sB[buf ^ 1][1][0], t + 1, 1); } }
        else         { if (t + 2 < NT) { stageA(&sA[buf][0][0], t + 2, 0);
                                         stageB(&sB[buf][0][0], t + 2, 0); } }

        __builtin_amdgcn_s_barrier();
        asm volatile("s_waitcnt lgkmcnt(0)" ::: "memory");
        __builtin_amdgcn_s_setprio(1);
        #pragma unroll
        for (int nf = 0; nf < 4; ++nf)
          #pragma unroll
          for (int mf = 0; mf < 4; ++mf)
            acc[mf][nf] = __builtin_amdgcn_mfma_f32_16x16x32_bf16(
                afrag[mf], bfrag[nf], acc[mf][nf], 0, 0, 0);
        __builtin_amdgcn_s_setprio(0);
        if (ph == 1) {
          if (t + 2 < NT) asm volatile("s_waitcnt vmcnt(3)" ::: "memory");
          else            asm volatile("s_waitcnt vmcnt(0)" ::: "memory");
        }
        __builtin_amdgcn_s_barrier();
      }
    }

    #pragma unroll
    for (int mf = 0; mf < 4; ++mf) {
      const int row = bm + wm * 64 + mf * 16 + quad * 4;
      #pragma unroll
      for (int nf = 0; nf < 4; ++nf) {
        const int col = bn + wn * 64 + nf * 16 + l16;
        #pragma unroll
        for (int rr = 0; rr < 4; ++rr)
          Cout[(size_t)(row + rr) * N + col] = f2bf(acc[mf][nf][rr]);
      }
    }
  }
}

// ---------------- out-projection: 256x128 tiles, 256 blocks = ONE full-machine round ----------
// Mirror of the verified light path (A=256 rows/2 issues, B=128 rows/1 issue), 8 waves 4Mx2N,
// 2 fat phases/K-tile, counted vmcnt(3). Writes f32.
__global__ __launch_bounds__(512, 2) void gemm_out(const unsigned short* __restrict__ A,
                                                   const unsigned short* __restrict__ Bt,
                                                   float* __restrict__ C,
                                                   int M, int N, int K) {
  __shared__ unsigned short sA[2][2][256 * 32];   // 64 KB
  __shared__ unsigned short sB[2][2][128 * 32];   // 32 KB
  const int id   = blockIdx.x;
  const int tid  = threadIdx.x;
  const int lane = tid & 63;
  const int wid  = tid >> 6;
  const int l16 = lane & 15, quad = lane >> 4;
  const int col16 = quad ^ ((lane >> 1) & 3);
  const int qk_log = (lane & 3) ^ ((lane >> 3) & 3);
  const int srow = lane >> 2;
  const int NT = K >> 6;
  const int bm = (id >> 4) * 256, bn = (id & 15) * 128;
  const int wm = wid >> 1, wn = wid & 1;           // wave tile: rows wm*64 (of 256), cols wn*64 (of 128)

  f32x4 acc[4][4];
  #pragma unroll
  for (int i = 0; i < 4; ++i)
    #pragma unroll
    for (int j = 0; j < 4; ++j)
      acc[i][j] = (f32x4){0.f, 0.f, 0.f, 0.f};

  auto stageA = [&](unsigned short* l, int t, int kh) {     // 256 rows, 2 issues/wave
    const unsigned short* src = A + (size_t)bm * K + t * 64 + kh * 32 + qk_log * 8;
    #pragma unroll
    for (int p = 0; p < 2; ++p) {
      const int i = wid * 2 + p;
      gld16(src + (size_t)(i * 16 + srow) * K, l + i * 512);
    }
  };
  auto stageB = [&](unsigned short* l, int t, int kh) {     // 128 rows, 1 issue/wave
    const unsigned short* src = Bt + (size_t)bn * K + t * 64 + kh * 32 + qk_log * 8;
    gld16(src + (size_t)(wid * 16 + srow) * K, l + wid * 512);
  };

  stageA(&sA[0][0][0], 0, 0); stageB(&sB[0][0][0], 0, 0);
  stageA(&sA[0][1][0], 0, 1); stageB(&sB[0][1][0], 0, 1);
  stageA(&sA[1][0][0], 1, 0); stageB(&sB[1][0][0], 1, 0);
  asm volatile("s_waitcnt vmcnt(3)" ::: "memory");
  __builtin_amdgcn_s_barrier();

  for (int t = 0; t < NT; ++t) {
    const int buf = t & 1;
    #pragma unroll
    for (int ph = 0; ph < 2; ++ph) {
      bf16x8 afrag[4], bfrag[4];
      const unsigned short* aP = &sA[buf][ph][0] +
          (size_t)((wm * 64 + l16) * 4 + col16) * 8;
      #pragma unroll
      for (int mf = 0; mf < 4; ++mf)
        afrag[mf] = *(const bf16x8*)(aP + mf * 512);
      const unsigned short* bP = &sB[buf][ph][0] +
          (size_t)((wn * 64 + l16) * 4 + col16) * 8;
      #pragma unroll
      for (int nf = 0; nf < 4; ++nf)
        bfrag[nf] = *(const bf16x8*)(bP + nf * 512);

      if (ph == 0) { if (t + 1 < NT) { stageA(&sA[buf ^ 1][1][0], t + 1, 1);
                                       stageB(&sB[buf ^ 1][1][0], t + 1, 1); } }
      else         { if (t + 2 < NT) { stageA(&sA[buf][0][0], t + 2, 0);
                                       stageB(&sB[buf][0][0], t + 2, 0); } }

      __builtin_amdgcn_s_barrier();
      asm volatile("s_waitcnt lgkmcnt(0)" ::: "memory");
      __builtin_amdgcn_s_setprio(1);
      #pragma unroll
      for (int nf = 0; nf < 4; ++nf)
        #pragma unroll
        for (int mf = 0; mf < 4; ++mf)
          acc[mf][nf] = __builtin_amdgcn_mfma_f32_16x16x32_bf16(
              afrag[mf], bfrag[nf], acc[mf][nf], 0, 0, 0);
      __builtin_amdgcn_s_setprio(0);
      if (ph == 1) {
        if (t + 2 < NT) asm volatile("s_waitcnt vmcnt(3)" ::: "memory");
        else            asm volatile("s_waitcnt vmcnt(0)" ::: "memory");
      }
      __builtin_amdgcn_s_barrier();
    }
  }

  #pragma unroll
  for (int mf = 0; mf < 4; ++mf) {
    const int row = bm + wm * 64 + mf * 16 + quad * 4;
    #pragma unroll
    for (int nf = 0; nf < 4; ++nf) {
      const int col = bn + wn * 64 + nf * 16 + l16;
      #pragma unroll
      for (int rr = 0; rr < 4; ++rr)
        C[(size_t)(row + rr) * N + col] = acc[mf][nf][rr];
    }
  }
}

// ---------------- RoPE (in-place on bf16 Q and K), fast intrinsics + packed 4B I/O ----------------
__global__ void rope_kernel(unsigned short* __restrict__ Q, unsigned short* __restrict__ K,
                            const int* __restrict__ pos) {
  int idx = blockIdx.x * blockDim.x + threadIdx.x;
  int i = idx & 63;
  int h = (idx >> 6) & (H_ - 1);
  int s = (idx >> 10) & (S_ - 1);
  int b = idx >> 21;
  float p = (float)pos[s];
  float inv = __expf(-(float)i * (9.210340371976184f / 64.0f));
  float ang = p * inv;
  float sn, cs;
  __sincosf(ang, &sn, &cs);
  size_t base = (((size_t)b * S_ + s) * D_) + (size_t)h * DK_ + 2 * i;
  unsigned int q2 = *(const unsigned int*)(Q + base);
  float x1 = bf2f((unsigned short)(q2 & 0xffffu)), x2 = bf2f((unsigned short)(q2 >> 16));
  unsigned int lo = f2bf(x1 * cs - x2 * sn), hi = f2bf(x1 * sn + x2 * cs);
  *(unsigned int*)(Q + base) = lo | (hi << 16);
  unsigned int k2 = *(const unsigned int*)(K + base);
  x1 = bf2f((unsigned short)(k2 & 0xffffu)); x2 = bf2f((unsigned short)(k2 >> 16));
  lo = f2bf(x1 * cs - x2 * sn); hi = f2bf(x1 * sn + x2 * cs);
  *(unsigned int*)(K + base) = lo | (hi << 16);
}

// ---------------- V transpose: per b, VT[col][m] = V[m][col] ----------------
__global__ __launch_bounds__(256) void transpose_bf16(const unsigned short* __restrict__ src,
                                                      unsigned short* __restrict__ dst) {
  __shared__ unsigned short sT[64 * 64];
  const int b = blockIdx.y;
  const int tx = blockIdx.x & 31, ty = blockIdx.x >> 5;
  const size_t base = (size_t)b * 2048 * 2048;
  const int m0 = ty * 64, c0 = tx * 64;
  const int tid = threadIdx.x;
  #pragma unroll
  for (int c = 0; c < 2; ++c) {
    int idx = tid + c * 256;
    int row = idx >> 3;               // 0..63 (m)
    int chk = idx & 7;                // col chunk
    uint4 v = *(const uint4*)(src + base + (size_t)(m0 + row) * 2048 + c0 + chk * 8);
    *(uint4*)(sT + row * 64 + ((chk ^ (row & 7)) * 8)) = v;
  }
  __syncthreads();
  #pragma unroll
  for (int c = 0; c < 2; ++c) {
    int idx = tid + c * 256;
    int orow = idx >> 3;              // output row = col index
    int ocol = (idx & 7) * 8;         // output col = m index
    unsigned short tmp[8];
    #pragma unroll
    for (int j = 0; j < 8; ++j) {
      int lr = ocol + j;              // logical row (m)
      int lc = orow;                  // logical col
      tmp[j] = sT[lr * 64 + (((lc >> 3) ^ (lr & 7)) * 8) + (lc & 7)];
    }
    *(uint4*)(dst + base + (size_t)(c0 + orow) * 2048 + m0 + ocol) = *(const uint4*)tmp;
  }
}

// ---------------- Flash attention (causal), 32x32 MFMA, pipelined staging ----------------
__global__ __launch_bounds__(256, 2) void flash_attn(const unsigned short* __restrict__ Q,
                                                     const unsigned short* __restrict__ K,
                                                     const unsigned short* __restrict__ VT,
                                                     unsigned short* __restrict__ O) {
  __shared__ unsigned short sK[2][64 * 128];   // [buf][key][feat-chunk swz] 16KB each
  __shared__ unsigned short sVT[2][128 * 64];  // [buf][feat][key-chunk swz] 16KB each
  __shared__ unsigned short sP[4][32 * 64];    // per-wave 32x64 P, swz, 4KB each

  const int tid = threadIdx.x, lane = tid & 63, wid = tid >> 6;
  const int half = lane >> 5, l32 = lane & 31;
  const int qi = 15 - (blockIdx.x & 15);       // 16 q-blocks of 128 rows; heavy first
  const int bh = blockIdx.x >> 4;
  const int h = bh & (H_ - 1), b = bh >> 4;
  const int qw = qi * 128 + wid * 32;          // this wave's first Q row
  const size_t qkbase = ((size_t)b * S_) * D_ + (size_t)h * DK_;
  const unsigned short* Qg = Q + qkbase;
  const unsigned short* Kg = K + qkbase;
  const unsigned short* VTg = VT + (size_t)bh * DK_ * S_;   // [dk][s]
  unsigned short* Og = O + qkbase;
  unsigned short* sPw = sP[wid];

  const int kKeySub = lane >> 4;               // K: 4 key rows per issue
  const int kPhys   = lane & 15;               // 16 chunks per 256B K row
  const int vFeatSub = lane >> 3;              // VT: 8 feat rows per issue
  const int vPhys    = lane & 7;               // 8 chunks per 128B VT row

  bf16x8 qf[8];
  #pragma unroll
  for (int ks = 0; ks < 8; ++ks)
    qf[ks] = *(const bf16x8*)(Qg + (size_t)(qw + l32) * D_ + ks * 16 + half * 8);

  union { unsigned short u[8]; bf16x8 v; } onesu;
  #pragma unroll
  for (int j2 = 0; j2 < 8; ++j2) onesu.u[j2] = 0x3F80;  // bf16 1.0
  const bf16x8 ones = onesu.v;

  f32x16 Oacc[4];
  #pragma unroll
  for (int ft = 0; ft < 4; ++ft)
    #pragma unroll
    for (int r = 0; r < 16; ++r) Oacc[ft][r] = 0.f;
  f32x16 l_acc;
  #pragma unroll
  for (int r = 0; r < 16; ++r) l_acc[r] = 0.f;
  const float scale = 0.08838834764831845f;    // 1/sqrt(128)

  const int nkb = 2 * (qi + 1);

  auto stage = [&](int kb) {
    const int k0 = kb * 64;
    unsigned short* bK = sK[kb & 1];
    unsigned short* bV = sVT[kb & 1];
    #pragma unroll
    for (int p = 0; p < 4; ++p) {
      int issue = wid * 4 + p;                 // 0..15
      int key = issue * 4 + kKeySub;
      int logiK = (kPhys & 8) | ((kPhys ^ key) & 7);
      gld16(Kg + (size_t)(k0 + key) * D_ + logiK * 8, bK + issue * 512);
      int feat = issue * 8 + vFeatSub;
      int logiV = vPhys ^ (feat & 7);
      gld16(VTg + (size_t)feat * S_ + k0 + logiV * 8, bV + issue * 512);
    }
  };

  stage(0);

  for (int kb = 0; kb < nkb; ++kb) {
    __syncthreads();   // drains vmcnt: buf[kb&1] ready; prior reads of other buf done
    if (kb + 1 < nkb) stage(kb + 1);

    const int k0 = kb * 64;
    if (k0 > qw + 31) continue;                // fully-masked for this wave (uniform)

    const unsigned short* bK = sK[kb & 1];
    const unsigned short* bV = sVT[kb & 1];

    f32x16 sc[2];
    #pragma unroll
    for (int t = 0; t < 2; ++t)
      #pragma unroll
      for (int r = 0; r < 16; ++r) sc[t][r] = 0.f;
    __builtin_amdgcn_s_setprio(1);
    #pragma unroll
    for (int ks = 0; ks < 8; ++ks) {
      const int logi = ks * 2 + half;
      #pragma unroll
      for (int t = 0; t < 2; ++t) {
        const int key = t * 32 + l32;
        const int phys = (logi & 8) | ((logi ^ key) & 7);
        bf16x8 kf = *(const bf16x8*)(bK + key * 128 + phys * 8);
        sc[t] = __builtin_amdgcn_mfma_f32_32x32x16_bf16(qf[ks], kf, sc[t], 0, 0, 0);
      }
    }
    __builtin_amdgcn_s_setprio(0);

    const bool diag = (k0 + 63 > qw);
    #pragma unroll
    for (int t = 0; t < 2; ++t) {
      const int col = t * 32 + l32;
      const int keyg = k0 + col;
      #pragma unroll
      for (int r = 0; r < 16; ++r) {
        const int rl = (r & 3) + 8 * (r >> 2) + 4 * half;
        float v = sc[t][r] * scale;
        if (diag && (keyg > qw + rl)) v = -1e30f;
        sPw[rl * 64 + (((col >> 3) ^ (rl & 7)) * 8) + (col & 7)] = f2bf(__expf(v));
      }
    }

    __builtin_amdgcn_s_setprio(1);
    #pragma unroll
    for (int ksp = 0; ksp < 4; ++ksp) {
      const int logi = ksp * 2 + half;
      bf16x8 pf = *(const bf16x8*)(sPw + l32 * 64 + ((logi ^ (l32 & 7)) * 8));
      l_acc = __builtin_amdgcn_mfma_f32_32x32x16_bf16(pf, ones, l_acc, 0, 0, 0);
      #pragma unroll
      for (int ft = 0; ft < 4; ++ft) {
        const int feat = ft * 32 + l32;
        const int phys = logi ^ (feat & 7);
        bf16x8 vf = *(const bf16x8*)(bV + feat * 64 + phys * 8);
        Oacc[ft] = __builtin_amdgcn_mfma_f32_32x32x16_bf16(pf, vf, Oacc[ft], 0, 0, 0);
      }
    }
    __builtin_amdgcn_s_setprio(0);
  }

  #pragma unroll
  for (int ft = 0; ft < 4; ++ft) {
    const int feat = ft * 32 + l32;
    #pragma unroll
    for (int r = 0; r < 16; ++r) {
      const int rl = (r & 3) + 8 * (r >> 2) + 4 * half;
      Og[(size_t)(qw + rl) * D_ + feat] = f2bf(Oacc[ft][r] / l_acc[r]);
    }
  }
}

// ---------------- launch ----------------
extern "C" void kernel_launch(void* const* d_in, const int* in_sizes, int n_in,
                              void* d_out, int out_size, void* d_ws, size_t ws_size,
                              hipStream_t stream) {
  const float* x  = (const float*)d_in[0];
  const float* Wq = (const float*)d_in[1];
  const float* Wk = (const float*)d_in[2];
  const float* Wv = (const float*)d_in[3];
  const float* Wo = (const float*)d_in[4];
  const int*  pos = (const int*)d_in[5];
  float* out = (float*)d_out;

  char* ws = (char*)d_ws;
  size_t off = 0;
  auto alloc = [&](size_t bytes) { void* p = ws + off; off += (bytes + 255) & ~255ULL; return p; };
  const size_t nx = (size_t)M_ * D_;
  const size_t nw = (size_t)D_ * D_;
  unsigned short* xb  = (unsigned short*)alloc(nx * 2);
  unsigned short* wqb = (unsigned short*)alloc(nw * 2);
  unsigned short* wkb = (unsigned short*)alloc(nw * 2);
  unsigned short* wvb = (unsigned short*)alloc(nw * 2);
  unsigned short* wob = (unsigned short*)alloc(nw * 2);
  unsigned short* Qb  = (unsigned short*)alloc(nx * 2);
  unsigned short* Kb  = (unsigned short*)alloc(nx * 2);
  unsigned short* Vb  = (unsigned short*)alloc(nx * 2);
  unsigned short* AOb = xb;   // alias: x_bf16 dead after QKV projection
  unsigned short* VTb = wqb;  // alias: Wq/Wk bf16 dead after QKV projection

  // single fused cvt: dst regions xb|wqb|wkb|wvb|wob are contiguous
  hipLaunchKernelGGL(cvt_all, dim3((nx + 4 * nw) / 1024), dim3(256), 0, stream,
                     x, Wq, Wk, Wv, Wo, xb);

  // fused QKV projection: one 512-block dispatch (256 heavy QK + 256 light V tiles)
  hipLaunchKernelGGL(gemm_qkv, dim3(512), dim3(512), 0, stream,
                     xb, wqb, wkb, wvb, Qb, Kb, Vb, M_, D_, D_);

  hipLaunchKernelGGL(rope_kernel, dim3((B_ * S_ * H_ * 64) / 256), dim3(256), 0, stream, Qb, Kb, pos);

  // V -> VT (per-b 2048x2048 transpose), into dead Wq/Wk bf16 space
  hipLaunchKernelGGL(transpose_bf16, dim3(1024, 2), dim3(256), 0, stream, Vb, VTb);

  hipLaunchKernelGGL(flash_attn, dim3(B_ * H_ * (S_ / 128)), dim3(256), 0, stream, Qb, Kb, VTb, AOb);

  // out-projection: 256x128 tiles, 256 blocks = one full-machine round
  hipLaunchKernelGGL(gemm_out, dim3((M_ / 256) * (D_ / 128)), dim3(512), 0, stream,
                     AOb, wob, out, M_, D_, D_);
}

// Round 7
// 392.026 us; speedup vs baseline: 1.1724x; 1.0493x over previous
//
#include <hip/hip_runtime.h>
#include <hip/hip_bf16.h>
#include <cstdint>
#include <cstddef>

#define B_ 2
#define S_ 2048
#define D_ 2048
#define H_ 16
#define DK_ 128
#define M_ (B_*S_)   // 4096

typedef __attribute__((ext_vector_type(8))) __bf16 bf16x8;
typedef __attribute__((ext_vector_type(4))) float f32x4;
typedef __attribute__((ext_vector_type(16))) float f32x16;

__device__ __forceinline__ unsigned short f2bf(float f) {
  union { float f; unsigned int u; } v; v.f = f;
  unsigned int r = (v.u + 0x7fffu + ((v.u >> 16) & 1u)) >> 16;
  return (unsigned short)r;
}
__device__ __forceinline__ float bf2f(unsigned short b) {
  union { unsigned int u; float f; } v; v.u = ((unsigned int)b) << 16;
  return v.f;
}

// async global->LDS, 16B per lane; LDS dest is wave-uniform base + lane*16
__device__ __forceinline__ void gld16(const void* g, void* l) {
  __builtin_amdgcn_global_load_lds(
      (const __attribute__((address_space(1))) unsigned int*)g,
      (__attribute__((address_space(3))) unsigned int*)l, 16, 0, 0);
}

// ---------------- fused fp32 -> bf16 for x|Wq|Wk|Wv|Wo (contiguous dst) ----------------
__global__ void cvt_all(const float* __restrict__ x,  const float* __restrict__ Wq,
                        const float* __restrict__ Wk, const float* __restrict__ Wv,
                        const float* __restrict__ Wo, unsigned short* __restrict__ dst) {
  size_t i = ((size_t)blockIdx.x * blockDim.x + threadIdx.x) * 4;
  const float* src;
  size_t off;
  if (i < ((size_t)M_ * D_)) {            // x region (2^23)
    src = x; off = i;
  } else {
    size_t j = i - (size_t)M_ * D_;
    int w = (int)(j >> 22);               // nw = 2^22
    off = j & ((1u << 22) - 1);
    src = (w == 0) ? Wq : (w == 1) ? Wk : (w == 2) ? Wv : Wo;
  }
  float4 v = *(const float4*)(src + off);
  dst[i+0] = f2bf(v.x); dst[i+1] = f2bf(v.y);
  dst[i+2] = f2bf(v.z); dst[i+3] = f2bf(v.w);
}

// ---------------- QKV projection, single 512-block dispatch ----------------
// Blocks 0..255: Q (z=0) / K (z=1) at 256x256 tiles, 8-phase schedule,
//                with RoPE fused into the epilogue (pair = adjacent lanes, shfl_xor(1)).
// Blocks 256..511: V at 128x256 tiles, 2 fat phases/K-tile, vmcnt(3),
//                with the V->VT transpose fused into the epilogue (writes [bh][dk][s]).
__global__ __launch_bounds__(512, 2) void gemm_qkv(const unsigned short* __restrict__ A,
                                                   const unsigned short* __restrict__ W0,
                                                   const unsigned short* __restrict__ W1,
                                                   const unsigned short* __restrict__ W2,
                                                   unsigned short* __restrict__ C0,
                                                   unsigned short* __restrict__ C1,
                                                   unsigned short* __restrict__ CVT,
                                                   const int* __restrict__ pos,
                                                   int M, int N, int K) {
  __shared__ unsigned short sA[2][2][256 * 32];   // [buf][khalf][rows x 32 k]
  __shared__ unsigned short sB[2][2][256 * 32];
  const int id   = blockIdx.x;
  const int tid  = threadIdx.x;
  const int lane = tid & 63;
  const int wid  = tid >> 6;
  const int l16 = lane & 15, quad = lane >> 4;
  const int col16 = quad ^ ((lane >> 1) & 3);        // swizzled 16B chunk for frag reads
  const int qk_log = (lane & 3) ^ ((lane >> 3) & 3); // inverse swizzle for staging source
  const int srow = lane >> 2;                        // staging row within 16-row group
  const int NT = K >> 6;                             // K-tiles of 64

  if (id < 256) {
    // ---------------- heavy path: 256x256, Q/K + fused RoPE ----------------
    const int z = id >> 7, r = id & 127;
    const unsigned short* Bt = z ? W1 : W0;
    unsigned short* Cout = z ? C1 : C0;
    const int bm = (r >> 3) * 256, bn = (r & 7) * 256;
    const int wm = wid >> 2, wn = wid & 3;           // wave tile: rows wm*128, cols wn*64

    f32x4 acc[8][4];
    #pragma unroll
    for (int i = 0; i < 8; ++i)
      #pragma unroll
      for (int j = 0; j < 4; ++j)
        acc[i][j] = (f32x4){0.f, 0.f, 0.f, 0.f};

    auto stage = [&](const unsigned short* __restrict__ g, int rowbase,
                     unsigned short* l, int t, int kh) {
      const unsigned short* src = g + (size_t)rowbase * K + t * 64 + kh * 32 + qk_log * 8;
      #pragma unroll
      for (int p = 0; p < 2; ++p) {
        const int i = wid * 2 + p;                   // issue 0..15, 16 rows each
        gld16(src + (size_t)(i * 16 + srow) * K, l + i * 512);
      }
    };

    stage(A,  bm, &sA[0][0][0], 0, 0);
    stage(Bt, bn, &sB[0][0][0], 0, 0);
    stage(A,  bm, &sA[0][1][0], 0, 1);
    stage(Bt, bn, &sB[0][1][0], 0, 1);
    stage(A,  bm, &sA[1][0][0], 1, 0);
    stage(Bt, bn, &sB[1][0][0], 1, 0);
    asm volatile("s_waitcnt vmcnt(4)" ::: "memory");
    __builtin_amdgcn_s_barrier();

    for (int t = 0; t < NT; ++t) {
      const int buf = t & 1;
      bf16x8 bfrag[4];
      #pragma unroll
      for (int ph = 0; ph < 4; ++ph) {
        const int ks = ph >> 1;
        const int mh = ph & 1;
        bf16x8 afrag[4];
        const unsigned short* aP = &sA[buf][ks][0] +
            (size_t)((wm * 128 + mh * 64 + l16) * 4 + col16) * 8;
        #pragma unroll
        for (int mf = 0; mf < 4; ++mf)
          afrag[mf] = *(const bf16x8*)(aP + mf * 512);
        if (mh == 0) {
          const unsigned short* bP = &sB[buf][ks][0] +
              (size_t)((wn * 64 + l16) * 4 + col16) * 8;
          #pragma unroll
          for (int nf = 0; nf < 4; ++nf)
            bfrag[nf] = *(const bf16x8*)(bP + nf * 512);
        }
        if (ph == 0)      { if (t + 1 < NT) stage(A,  bm, &sA[buf ^ 1][1][0], t + 1, 1); }
        else if (ph == 1) { if (t + 1 < NT) stage(Bt, bn, &sB[buf ^ 1][1][0], t + 1, 1); }
        else if (ph == 2) { if (t + 2 < NT) stage(A,  bm, &sA[buf][0][0],     t + 2, 0); }
        else              { if (t + 2 < NT) stage(Bt, bn, &sB[buf][0][0],     t + 2, 0); }

        __builtin_amdgcn_s_barrier();
        asm volatile("s_waitcnt lgkmcnt(0)" ::: "memory");
        __builtin_amdgcn_s_setprio(1);
        #pragma unroll
        for (int nf = 0; nf < 4; ++nf)
          #pragma unroll
          for (int mf = 0; mf < 4; ++mf)
            acc[mh * 4 + mf][nf] = __builtin_amdgcn_mfma_f32_16x16x32_bf16(
                afrag[mf], bfrag[nf], acc[mh * 4 + mf][nf], 0, 0, 0);
        __builtin_amdgcn_s_setprio(0);
        if (ph == 3) {
          if (t + 2 < NT) asm volatile("s_waitcnt vmcnt(4)" ::: "memory");
          else            asm volatile("s_waitcnt vmcnt(0)" ::: "memory");
        }
        __builtin_amdgcn_s_barrier();
      }
    }

    // fused RoPE: col parity == lane parity; partner value via shfl_xor(1).
    float invf[4];
    #pragma unroll
    for (int nf = 0; nf < 4; ++nf) {
      const int i = (((wn & 1) * 64) + nf * 16 + l16) >> 1;   // (col & 127) >> 1
      invf[nf] = __expf(-(float)i * (9.210340371976184f / 64.0f));
    }
    const float ssgn = (lane & 1) ? 1.0f : -1.0f;
    #pragma unroll
    for (int mf = 0; mf < 8; ++mf) {
      const int row = bm + wm * 128 + mf * 16 + quad * 4;
      #pragma unroll
      for (int rr = 0; rr < 4; ++rr) {
        const float p = (float)pos[(row + rr) & (S_ - 1)];
        #pragma unroll
        for (int nf = 0; nf < 4; ++nf) {
          float sn, cs;
          __sincosf(p * invf[nf], &sn, &cs);
          const float v = acc[mf][nf][rr];
          const float xo = __shfl_xor(v, 1);
          acc[mf][nf][rr] = v * cs + xo * (sn * ssgn);
        }
      }
    }

    #pragma unroll
    for (int mf = 0; mf < 8; ++mf) {
      const int row = bm + wm * 128 + mf * 16 + quad * 4;
      #pragma unroll
      for (int nf = 0; nf < 4; ++nf) {
        const int col = bn + wn * 64 + nf * 16 + l16;
        #pragma unroll
        for (int rr = 0; rr < 4; ++rr)
          Cout[(size_t)(row + rr) * N + col] = f2bf(acc[mf][nf][rr]);
      }
    }
  } else {
    // ---------------- light path: 128x256, V; writes VT[bh][dk][s] directly -----------
    const int r = id - 256;
    const unsigned short* Bt = W2;
    const int bm = (r >> 3) * 128, bn = (r & 7) * 256;
    const int wm = wid >> 2, wn = wid & 3;           // wave tile: rows wm*64, cols wn*64

    f32x4 acc[4][4];
    #pragma unroll
    for (int i = 0; i < 4; ++i)
      #pragma unroll
      for (int j = 0; j < 4; ++j)
        acc[i][j] = (f32x4){0.f, 0.f, 0.f, 0.f};

    auto stageB = [&](unsigned short* l, int t, int kh) {   // 256 rows, 2 issues/wave
      const unsigned short* src = Bt + (size_t)bn * K + t * 64 + kh * 32 + qk_log * 8;
      #pragma unroll
      for (int p = 0; p < 2; ++p) {
        const int i = wid * 2 + p;
        gld16(src + (size_t)(i * 16 + srow) * K, l + i * 512);
      }
    };
    auto stageA = [&](unsigned short* l, int t, int kh) {   // 128 rows, 1 issue/wave
      const unsigned short* src = A + (size_t)bm * K + t * 64 + kh * 32 + qk_log * 8;
      gld16(src + (size_t)(wid * 16 + srow) * K, l + wid * 512);
    };

    stageA(&sA[0][0][0], 0, 0); stageB(&sB[0][0][0], 0, 0);
    stageA(&sA[0][1][0], 0, 1); stageB(&sB[0][1][0], 0, 1);
    stageA(&sA[1][0][0], 1, 0); stageB(&sB[1][0][0], 1, 0);
    asm volatile("s_waitcnt vmcnt(3)" ::: "memory");
    __builtin_amdgcn_s_barrier();

    for (int t = 0; t < NT; ++t) {
      const int buf = t & 1;
      #pragma unroll
      for (int ph = 0; ph < 2; ++ph) {               // ph = K-half consumed
        bf16x8 afrag[4], bfrag[4];
        const unsigned short* aP = &sA[buf][ph][0] +
            (size_t)((wm * 64 + l16) * 4 + col16) * 8;
        #pragma unroll
        for (int mf = 0; mf < 4; ++mf)
          afrag[mf] = *(const bf16x8*)(aP + mf * 512);
        const unsigned short* bP = &sB[buf][ph][0] +
            (size_t)((wn * 64 + l16) * 4 + col16) * 8;
        #pragma unroll
        for (int nf = 0; nf < 4; ++nf)
          bfrag[nf] = *(const bf16x8*)(bP + nf * 512);

        if (ph == 0) { if (t + 1 < NT) { stageA(&sA[buf ^ 1][1][0], t + 1, 1);
                                         stageB(&sB[buf ^ 1][1][0], t + 1, 1); } }
        else         { if (t + 2 < NT) { stageA(&sA[buf][0][0], t + 2, 0);
                                         stageB(&sB[buf][0][0], t + 2, 0); } }

        __builtin_amdgcn_s_barrier();
        asm volatile("s_waitcnt lgkmcnt(0)" ::: "memory");
        __builtin_amdgcn_s_setprio(1);
        #pragma unroll
        for (int nf = 0; nf < 4; ++nf)
          #pragma unroll
          for (int mf = 0; mf < 4; ++mf)
            acc[mf][nf] = __builtin_amdgcn_mfma_f32_16x16x32_bf16(
                afrag[mf], bfrag[nf], acc[mf][nf], 0, 0, 0);
        __builtin_amdgcn_s_setprio(0);
        if (ph == 1) {
          if (t + 2 < NT) asm volatile("s_waitcnt vmcnt(3)" ::: "memory");
          else            asm volatile("s_waitcnt vmcnt(0)" ::: "memory");
        }
        __builtin_amdgcn_s_barrier();
      }
    }

    // fused transpose: VT[(b*16+h)*128 + dk][s] ; 4 consecutive s per thread -> 8B store
    #pragma unroll
    for (int mf = 0; mf < 4; ++mf) {
      const int row = bm + wm * 64 + mf * 16 + quad * 4;
      const int s = row & (S_ - 1), bidx = row >> 11;
      #pragma unroll
      for (int nf = 0; nf < 4; ++nf) {
        const int col = bn + wn * 64 + nf * 16 + l16;
        const int bh = bidx * 16 + (col >> 7);
        const int dk = col & 127;
        unsigned short tmp[4];
        #pragma unroll
        for (int rr = 0; rr < 4; ++rr) tmp[rr] = f2bf(acc[mf][nf][rr]);
        *(uint2*)(CVT + ((size_t)bh * DK_ + dk) * S_ + s) = *(const uint2*)tmp;
      }
    }
  }
}

// ---------------- out-projection: 256x128 tiles, 256 blocks = ONE full-machine round ----------
__global__ __launch_bounds__(512, 2) void gemm_out(const unsigned short* __restrict__ A,
                                                   const unsigned short* __restrict__ Bt,
                                                   float* __restrict__ C,
                                                   int M, int N, int K) {
  __shared__ unsigned short sA[2][2][256 * 32];   // 64 KB
  __shared__ unsigned short sB[2][2][128 * 32];   // 32 KB
  const int id   = blockIdx.x;
  const int tid  = threadIdx.x;
  const int lane = tid & 63;
  const int wid  = tid >> 6;
  const int l16 = lane & 15, quad = lane >> 4;
  const int col16 = quad ^ ((lane >> 1) & 3);
  const int qk_log = (lane & 3) ^ ((lane >> 3) & 3);
  const int srow = lane >> 2;
  const int NT = K >> 6;
  const int bm = (id >> 4) * 256, bn = (id & 15) * 128;
  const int wm = wid >> 1, wn = wid & 1;

  f32x4 acc[4][4];
  #pragma unroll
  for (int i = 0; i < 4; ++i)
    #pragma unroll
    for (int j = 0; j < 4; ++j)
      acc[i][j] = (f32x4){0.f, 0.f, 0.f, 0.f};

  auto stageA = [&](unsigned short* l, int t, int kh) {     // 256 rows, 2 issues/wave
    const unsigned short* src = A + (size_t)bm * K + t * 64 + kh * 32 + qk_log * 8;
    #pragma unroll
    for (int p = 0; p < 2; ++p) {
      const int i = wid * 2 + p;
      gld16(src + (size_t)(i * 16 + srow) * K, l + i * 512);
    }
  };
  auto stageB = [&](unsigned short* l, int t, int kh) {     // 128 rows, 1 issue/wave
    const unsigned short* src = Bt + (size_t)bn * K + t * 64 + kh * 32 + qk_log * 8;
    gld16(src + (size_t)(wid * 16 + srow) * K, l + wid * 512);
  };

  stageA(&sA[0][0][0], 0, 0); stageB(&sB[0][0][0], 0, 0);
  stageA(&sA[0][1][0], 0, 1); stageB(&sB[0][1][0], 0, 1);
  stageA(&sA[1][0][0], 1, 0); stageB(&sB[1][0][0], 1, 0);
  asm volatile("s_waitcnt vmcnt(3)" ::: "memory");
  __builtin_amdgcn_s_barrier();

  for (int t = 0; t < NT; ++t) {
    const int buf = t & 1;
    #pragma unroll
    for (int ph = 0; ph < 2; ++ph) {
      bf16x8 afrag[4], bfrag[4];
      const unsigned short* aP = &sA[buf][ph][0] +
          (size_t)((wm * 64 + l16) * 4 + col16) * 8;
      #pragma unroll
      for (int mf = 0; mf < 4; ++mf)
        afrag[mf] = *(const bf16x8*)(aP + mf * 512);
      const unsigned short* bP = &sB[buf][ph][0] +
          (size_t)((wn * 64 + l16) * 4 + col16) * 8;
      #pragma unroll
      for (int nf = 0; nf < 4; ++nf)
        bfrag[nf] = *(const bf16x8*)(bP + nf * 512);

      if (ph == 0) { if (t + 1 < NT) { stageA(&sA[buf ^ 1][1][0], t + 1, 1);
                                       stageB(&sB[buf ^ 1][1][0], t + 1, 1); } }
      else         { if (t + 2 < NT) { stageA(&sA[buf][0][0], t + 2, 0);
                                       stageB(&sB[buf][0][0], t + 2, 0); } }

      __builtin_amdgcn_s_barrier();
      asm volatile("s_waitcnt lgkmcnt(0)" ::: "memory");
      __builtin_amdgcn_s_setprio(1);
      #pragma unroll
      for (int nf = 0; nf < 4; ++nf)
        #pragma unroll
        for (int mf = 0; mf < 4; ++mf)
          acc[mf][nf] = __builtin_amdgcn_mfma_f32_16x16x32_bf16(
              afrag[mf], bfrag[nf], acc[mf][nf], 0, 0, 0);
      __builtin_amdgcn_s_setprio(0);
      if (ph == 1) {
        if (t + 2 < NT) asm volatile("s_waitcnt vmcnt(3)" ::: "memory");
        else            asm volatile("s_waitcnt vmcnt(0)" ::: "memory");
      }
      __builtin_amdgcn_s_barrier();
    }
  }

  #pragma unroll
  for (int mf = 0; mf < 4; ++mf) {
    const int row = bm + wm * 64 + mf * 16 + quad * 4;
    #pragma unroll
    for (int nf = 0; nf < 4; ++nf) {
      const int col = bn + wn * 64 + nf * 16 + l16;
      #pragma unroll
      for (int rr = 0; rr < 4; ++rr)
        C[(size_t)(row + rr) * N + col] = acc[mf][nf][rr];
    }
  }
}

// ---------------- Flash attention (causal), 32x32 MFMA, pipelined staging ----------------
__global__ __launch_bounds__(256, 2) void flash_attn(const unsigned short* __restrict__ Q,
                                                     const unsigned short* __restrict__ K,
                                                     const unsigned short* __restrict__ VT,
                                                     unsigned short* __restrict__ O) {
  __shared__ unsigned short sK[2][64 * 128];   // [buf][key][feat-chunk swz] 16KB each
  __shared__ unsigned short sVT[2][128 * 64];  // [buf][feat][key-chunk swz] 16KB each
  __shared__ unsigned short sP[4][32 * 64];    // per-wave 32x64 P, swz, 4KB each

  const int tid = threadIdx.x, lane = tid & 63, wid = tid >> 6;
  const int half = lane >> 5, l32 = lane & 31;
  const int qi = 15 - (blockIdx.x & 15);       // 16 q-blocks of 128 rows; heavy first
  const int bh = blockIdx.x >> 4;
  const int h = bh & (H_ - 1), b = bh >> 4;
  const int qw = qi * 128 + wid * 32;          // this wave's first Q row
  const size_t qkbase = ((size_t)b * S_) * D_ + (size_t)h * DK_;
  const unsigned short* Qg = Q + qkbase;
  const unsigned short* Kg = K + qkbase;
  const unsigned short* VTg = VT + (size_t)bh * DK_ * S_;   // [dk][s]
  unsigned short* Og = O + qkbase;
  unsigned short* sPw = sP[wid];

  const int kKeySub = lane >> 4;               // K: 4 key rows per issue
  const int kPhys   = lane & 15;               // 16 chunks per 256B K row
  const int vFeatSub = lane >> 3;              // VT: 8 feat rows per issue
  const int vPhys    = lane & 7;               // 8 chunks per 128B VT row

  bf16x8 qf[8];
  #pragma unroll
  for (int ks = 0; ks < 8; ++ks)
    qf[ks] = *(const bf16x8*)(Qg + (size_t)(qw + l32) * D_ + ks * 16 + half * 8);

  union { unsigned short u[8]; bf16x8 v; } onesu;
  #pragma unroll
  for (int j2 = 0; j2 < 8; ++j2) onesu.u[j2] = 0x3F80;  // bf16 1.0
  const bf16x8 ones = onesu.v;

  f32x16 Oacc[4];
  #pragma unroll
  for (int ft = 0; ft < 4; ++ft)
    #pragma unroll
    for (int r = 0; r < 16; ++r) Oacc[ft][r] = 0.f;
  f32x16 l_acc;
  #pragma unroll
  for (int r = 0; r < 16; ++r) l_acc[r] = 0.f;
  const float scale = 0.08838834764831845f;    // 1/sqrt(128)

  const int nkb = 2 * (qi + 1);

  auto stage = [&](int kb) {
    const int k0 = kb * 64;
    unsigned short* bK = sK[kb & 1];
    unsigned short* bV = sVT[kb & 1];
    #pragma unroll
    for (int p = 0; p < 4; ++p) {
      int issue = wid * 4 + p;                 // 0..15
      int key = issue * 4 + kKeySub;
      int logiK = (kPhys & 8) | ((kPhys ^ key) & 7);
      gld16(Kg + (size_t)(k0 + key) * D_ + logiK * 8, bK + issue * 512);
      int feat = issue * 8 + vFeatSub;
      int logiV = vPhys ^ (feat & 7);
      gld16(VTg + (size_t)feat * S_ + k0 + logiV * 8, bV + issue * 512);
    }
  };

  stage(0);

  for (int kb = 0; kb < nkb; ++kb) {
    __syncthreads();   // drains vmcnt: buf[kb&1] ready; prior reads of other buf done
    if (kb + 1 < nkb) stage(kb + 1);

    const int k0 = kb * 64;
    if (k0 > qw + 31) continue;                // fully-masked for this wave (uniform)

    const unsigned short* bK = sK[kb & 1];
    const unsigned short* bV = sVT[kb & 1];

    f32x16 sc[2];
    #pragma unroll
    for (int t = 0; t < 2; ++t)
      #pragma unroll
      for (int r = 0; r < 16; ++r) sc[t][r] = 0.f;
    __builtin_amdgcn_s_setprio(1);
    #pragma unroll
    for (int ks = 0; ks < 8; ++ks) {
      const int logi = ks * 2 + half;
      #pragma unroll
      for (int t = 0; t < 2; ++t) {
        const int key = t * 32 + l32;
        const int phys = (logi & 8) | ((logi ^ key) & 7);
        bf16x8 kf = *(const bf16x8*)(bK + key * 128 + phys * 8);
        sc[t] = __builtin_amdgcn_mfma_f32_32x32x16_bf16(qf[ks], kf, sc[t], 0, 0, 0);
      }
    }
    __builtin_amdgcn_s_setprio(0);

    const bool diag = (k0 + 63 > qw);
    #pragma unroll
    for (int t = 0; t < 2; ++t) {
      const int col = t * 32 + l32;
      const int keyg = k0 + col;
      #pragma unroll
      for (int r = 0; r < 16; ++r) {
        const int rl = (r & 3) + 8 * (r >> 2) + 4 * half;
        float v = sc[t][r] * scale;
        if (diag && (keyg > qw + rl)) v = -1e30f;
        sPw[rl * 64 + (((col >> 3) ^ (rl & 7)) * 8) + (col & 7)] = f2bf(__expf(v));
      }
    }

    __builtin_amdgcn_s_setprio(1);
    #pragma unroll
    for (int ksp = 0; ksp < 4; ++ksp) {
      const int logi = ksp * 2 + half;
      bf16x8 pf = *(const bf16x8*)(sPw + l32 * 64 + ((logi ^ (l32 & 7)) * 8));
      l_acc = __builtin_amdgcn_mfma_f32_32x32x16_bf16(pf, ones, l_acc, 0, 0, 0);
      #pragma unroll
      for (int ft = 0; ft < 4; ++ft) {
        const int feat = ft * 32 + l32;
        const int phys = logi ^ (feat & 7);
        bf16x8 vf = *(const bf16x8*)(bV + feat * 64 + phys * 8);
        Oacc[ft] = __builtin_amdgcn_mfma_f32_32x32x16_bf16(pf, vf, Oacc[ft], 0, 0, 0);
      }
    }
    __builtin_amdgcn_s_setprio(0);
  }

  #pragma unroll
  for (int ft = 0; ft < 4; ++ft) {
    const int feat = ft * 32 + l32;
    #pragma unroll
    for (int r = 0; r < 16; ++r) {
      const int rl = (r & 3) + 8 * (r >> 2) + 4 * half;
      Og[(size_t)(qw + rl) * D_ + feat] = f2bf(Oacc[ft][r] / l_acc[r]);
    }
  }
}

// ---------------- launch ----------------
extern "C" void kernel_launch(void* const* d_in, const int* in_sizes, int n_in,
                              void* d_out, int out_size, void* d_ws, size_t ws_size,
                              hipStream_t stream) {
  const float* x  = (const float*)d_in[0];
  const float* Wq = (const float*)d_in[1];
  const float* Wk = (const float*)d_in[2];
  const float* Wv = (const float*)d_in[3];
  const float* Wo = (const float*)d_in[4];
  const int*  pos = (const int*)d_in[5];
  float* out = (float*)d_out;

  char* ws = (char*)d_ws;
  size_t off = 0;
  auto alloc = [&](size_t bytes) { void* p = ws + off; off += (bytes + 255) & ~255ULL; return p; };
  const size_t nx = (size_t)M_ * D_;
  const size_t nw = (size_t)D_ * D_;
  unsigned short* xb  = (unsigned short*)alloc(nx * 2);
  unsigned short* wqb = (unsigned short*)alloc(nw * 2);
  unsigned short* wkb = (unsigned short*)alloc(nw * 2);
  unsigned short* wvb = (unsigned short*)alloc(nw * 2);
  unsigned short* wob = (unsigned short*)alloc(nw * 2);
  unsigned short* Qb  = (unsigned short*)alloc(nx * 2);
  unsigned short* Kb  = (unsigned short*)alloc(nx * 2);
  unsigned short* VTb = (unsigned short*)alloc(nx * 2);   // VT written directly by gemm_qkv
  unsigned short* AOb = xb;   // alias: x_bf16 dead after QKV projection

  // single fused cvt: dst regions xb|wqb|wkb|wvb|wob are contiguous
  hipLaunchKernelGGL(cvt_all, dim3((nx + 4 * nw) / 1024), dim3(256), 0, stream,
                     x, Wq, Wk, Wv, Wo, xb);

  // fused QKV projection + RoPE (Q,K) + V-transpose: one 512-block dispatch
  hipLaunchKernelGGL(gemm_qkv, dim3(512), dim3(512), 0, stream,
                     xb, wqb, wkb, wvb, Qb, Kb, VTb, pos, M_, D_, D_);

  hipLaunchKernelGGL(flash_attn, dim3(B_ * H_ * (S_ / 128)), dim3(256), 0, stream, Qb, Kb, VTb, AOb);

  // out-projection: 256x128 tiles, 256 blocks = one full-machine round
  hipLaunchKernelGGL(gemm_out, dim3((M_ / 256) * (D_ / 128)), dim3(512), 0, stream,
                     AOb, wob, out, M_, D_, D_);
}